// Round 9
// baseline (945.509 us; speedup 1.0000x reference)
//
#include <hip/hip_runtime.h>
#include <math.h>

#define TT 64
#define FF 32
#define HH 64
#define NN 16     // nodes per block (two 8-node phase groups)
#define GG1 64
#define GG2 32

typedef float f32x4 __attribute__((ext_vector_type(4)));
typedef short bf16x8 __attribute__((ext_vector_type(8)));

__device__ __forceinline__ float fexp2(float x){ return __builtin_amdgcn_exp2f(x); }
__device__ __forceinline__ float frcp (float x){ return __builtin_amdgcn_rcpf(x); }
__device__ __forceinline__ float sigm (float v){ return frcp(1.0f + fexp2(-1.442695041f*v)); }
__device__ __forceinline__ float ftanh(float v){ return fmaf(-2.0f, frcp(1.0f + fexp2(2.885390082f*v)), 1.0f); }

// lane <-> lane^8 exchange within rows of 16 lanes (DPP row_ror:8, VALU pipe)
__device__ __forceinline__ float xor8(float v){
  int a = __builtin_bit_cast(int, v);
  int b = __builtin_amdgcn_update_dpp(0, a, 0x128, 0xF, 0xF, true);
  return __builtin_bit_cast(float, b);
}

__device__ __forceinline__ unsigned short bf16rn(float x){
  unsigned u = __builtin_bit_cast(unsigned, x);
  return (unsigned short)((u + 0x7FFFu + ((u >> 16) & 1u)) >> 16);
}
__device__ __forceinline__ void split2(float x, unsigned short& h, unsigned short& l){
  unsigned u = __builtin_bit_cast(unsigned, x);
  unsigned hr = (u + 0x7FFFu + ((u >> 16) & 1u)) & 0xFFFF0000u;
  h = (unsigned short)(hr >> 16);
  l = bf16rn(x - __builtin_bit_cast(float, hr));
}
// packed split of 2 values via v_cvt_pk_bf16_f32: hi2 = {bf16(b)<<16|bf16(a)}, lo2 likewise
__device__ __forceinline__ void split_pk(float a, float b, unsigned& hi2, unsigned& lo2){
  asm("v_cvt_pk_bf16_f32 %0, %1, %2" : "=v"(hi2) : "v"(a), "v"(b));
  float ha = __builtin_bit_cast(float, hi2 << 16);
  float hb = __builtin_bit_cast(float, hi2 & 0xFFFF0000u);
  float la = a - ha, lb = b - hb;
  asm("v_cvt_pk_bf16_f32 %0, %1, %2" : "=v"(lo2) : "v"(la), "v"(lb));
}

#define PIN(v) asm volatile("" : "+v"(v))
#define MFMA(acc, a, b) (acc) = __builtin_amdgcn_mfma_f32_16x16x32_bf16((a), (b), (acc), 0, 0, 0)

__device__ __forceinline__ void wsplit(const float* p, bf16x8& hi, bf16x8& lo){
  float4 a = *(const float4*)p;
  float4 b = *(const float4*)(p + 4);
  unsigned short h, s;
  split2(a.x,h,s); hi[0]=(short)h; lo[0]=(short)s;
  split2(a.y,h,s); hi[1]=(short)h; lo[1]=(short)s;
  split2(a.z,h,s); hi[2]=(short)h; lo[2]=(short)s;
  split2(a.w,h,s); hi[3]=(short)h; lo[3]=(short)s;
  split2(b.x,h,s); hi[4]=(short)h; lo[4]=(short)s;
  split2(b.y,h,s); hi[5]=(short)h; lo[5]=(short)s;
  split2(b.z,h,s); hi[6]=(short)h; lo[6]=(short)s;
  split2(b.w,h,s); hi[7]=(short)h; lo[7]=(short)s;
}

// ---------------------------------------------------------------------------
// Fused 2-layer LSTM, bf16 hi/lo emulated-fp32 MFMA (3-pass), two 8-node
// phase groups per block. Phase X(t): MFMA group A(t) || combine group B(t-1).
// Phase Y(t): MFMA B(t) || combine A(t). MFMA A-rows duplicate the 8 nodes
// into 16 rows; lanes lg<2 combine layer-0 cells from the L0 accs, lanes
// lg>=2 combine layer-1 cells from the (duplicated) L1 acc rows — one
// non-divergent combine path. 2 barriers/t, race-free by buffer x row
// disjointness. Weights in (A)GPRs as round 8.
// ---------------------------------------------------------------------------
__global__ __launch_bounds__(512, 2)
void lstm_mfma(const float* __restrict__ x,
    const float* __restrict__ Wih0, const float* __restrict__ Whh0,
    const float* __restrict__ bih0, const float* __restrict__ bhh0,
    const float* __restrict__ Wih1, const float* __restrict__ Whh1,
    const float* __restrict__ bih1, const float* __restrict__ bhh1,
    float* __restrict__ hout, int n)
{
  const int tid = threadIdx.x;
  const int w   = tid >> 6;     // wave 0..7
  const int l   = tid & 63;
  const int lr  = l & 15;       // A row-slot / B,D col-slot
  const int lg  = l >> 4;       // k-group 0..3
  const int nA  = blockIdx.x * NN;
  int avail = n - nA; if (avail > NN) avail = NN;

  __shared__ short Ax[2][2][16][40];   // [buf][pl][node][f]
  __shared__ short H0[2][2][16][88];   // [buf][pl][row][m]; rows 0-7 grp A, 8-15 grp B
  __shared__ short H1[2][2][16][88];

  const int jm   = lr & 7;
  const bool lo8 = (lr < 8);
  const int col0 = lo8 ? (8*w + jm) : (64  + 8*w + jm);     // i | f
  const int col1 = lo8 ? (128 + 8*w + jm) : (192 + 8*w + jm); // g | o

  // ---- weights -> split register fragments ----
  bf16x8 W0h[2][3], W0l[2][3], W1h[2][4], W1l[2][4];
  float bias0[2], bias1[2];
#pragma unroll
  for (int h = 0; h < 2; ++h){
    const int col = h ? col1 : col0;
    wsplit(Wih0 + col*FF + 8*lg,      W0h[h][0], W0l[h][0]);
    wsplit(Whh0 + col*HH + 8*lg,      W0h[h][1], W0l[h][1]);
    wsplit(Whh0 + col*HH + 32 + 8*lg, W0h[h][2], W0l[h][2]);
    wsplit(Wih1 + col*HH + 8*lg,      W1h[h][0], W1l[h][0]);
    wsplit(Wih1 + col*HH + 32 + 8*lg, W1h[h][1], W1l[h][1]);
    wsplit(Whh1 + col*HH + 8*lg,      W1h[h][2], W1l[h][2]);
    wsplit(Whh1 + col*HH + 32 + 8*lg, W1h[h][3], W1l[h][3]);
    bias0[h] = bih0[col] + bhh0[col];
    bias1[h] = bih1[col] + bhh1[col];
  }
#pragma unroll
  for (int h = 0; h < 2; ++h){
#pragma unroll
    for (int k = 0; k < 3; ++k){ PIN(W0h[h][k]); PIN(W0l[h][k]); }
#pragma unroll
    for (int k = 0; k < 4; ++k){ PIN(W1h[h][k]); PIN(W1l[h][k]); }
  }

  // combine role constants
  const int na    = 4*lg + (lo8 ? 0 : 2);  // 0..15: encodes (layer, local row pair)
  const int layer = na >> 3;               // lanes lg<2 -> layer0, lg>=2 -> layer1
  const int rwa   = na & 7;                // local node of cell a
  const int rwb   = (na + 1) & 7;          // local node of cell b
  const int m     = 8*w + jm;

  // ---- zero H planes; stage x(0) ----
  {
    short* p0 = &H0[0][0][0][0];
    short* p1 = &H1[0][0][0][0];
    for (int i = tid; i < 2*2*16*88; i += 512){ p0[i] = 0; p1[i] = 0; }
    const int xnd = tid >> 5, xf = tid & 31;
    float v = (xnd < avail) ? x[((size_t)(nA+xnd)*TT + 0)*FF + xf] : 0.0f;
    unsigned short hh, hl; split2(v, hh, hl);
    Ax[0][0][xnd][xf] = (short)hh;
    Ax[0][1][xnd][xf] = (short)hl;
  }
  float cAa = 0.0f, cAb = 0.0f, cBa = 0.0f, cBb = 0.0f;
  f32x4 aA0={0,0,0,0}, aA1={0,0,0,0}, dA0={0,0,0,0}, dA1={0,0,0,0};
  f32x4 aB0={0,0,0,0}, aB1={0,0,0,0}, dB0={0,0,0,0}, dB1={0,0,0,0};
  __syncthreads();

  // stage x(tp) for all 16 nodes (both groups)
  auto stageX = [&](int tp){
    if (tp < TT){
      const int xnd = tid >> 5, xf = tid & 31;
      float v = (xnd < avail) ? x[((size_t)(nA+xnd)*TT + tp)*FF + xf] : 0.0f;
      unsigned short hh, hl; split2(v, hh, hl);
      Ax[tp&1][0][xnd][xf] = (short)hh;
      Ax[tp&1][1][xnd][xf] = (short)hl;
    }
  };

  // MFMA phase for group g. A rows duplicate the group's 8 nodes.
  auto mfmaPh = [&](int g, int bufx, int rd0, int rd1, bool doL0, bool doL1,
                    f32x4& A0, f32x4& A1, f32x4& D0, f32x4& D1){
    const int rb = 8*g + (lr & 7);
    bf16x8 h0ah = *(const bf16x8*)&H0[rd0][0][rb][8*lg];
    bf16x8 h0al = *(const bf16x8*)&H0[rd0][1][rb][8*lg];
    bf16x8 h0bh = *(const bf16x8*)&H0[rd0][0][rb][32+8*lg];
    bf16x8 h0bl = *(const bf16x8*)&H0[rd0][1][rb][32+8*lg];
    if (doL0){
      bf16x8 axh = *(const bf16x8*)&Ax[bufx][0][rb][8*lg];
      bf16x8 axl = *(const bf16x8*)&Ax[bufx][1][rb][8*lg];
      A0 = (f32x4){bias0[0], bias0[0], bias0[0], bias0[0]};
      A1 = (f32x4){bias0[1], bias0[1], bias0[1], bias0[1]};
      MFMA(A0, axl,  W0h[0][0]); MFMA(A0, axh,  W0l[0][0]); MFMA(A0, axh,  W0h[0][0]);
      MFMA(A1, axl,  W0h[1][0]); MFMA(A1, axh,  W0l[1][0]); MFMA(A1, axh,  W0h[1][0]);
      MFMA(A0, h0al, W0h[0][1]); MFMA(A0, h0ah, W0l[0][1]); MFMA(A0, h0ah, W0h[0][1]);
      MFMA(A1, h0al, W0h[1][1]); MFMA(A1, h0ah, W0l[1][1]); MFMA(A1, h0ah, W0h[1][1]);
      MFMA(A0, h0bl, W0h[0][2]); MFMA(A0, h0bh, W0l[0][2]); MFMA(A0, h0bh, W0h[0][2]);
      MFMA(A1, h0bl, W0h[1][2]); MFMA(A1, h0bh, W0l[1][2]); MFMA(A1, h0bh, W0h[1][2]);
    }
    if (doL1){
      bf16x8 h1ah = *(const bf16x8*)&H1[rd1][0][rb][8*lg];
      bf16x8 h1al = *(const bf16x8*)&H1[rd1][1][rb][8*lg];
      bf16x8 h1bh = *(const bf16x8*)&H1[rd1][0][rb][32+8*lg];
      bf16x8 h1bl = *(const bf16x8*)&H1[rd1][1][rb][32+8*lg];
      D0 = (f32x4){bias1[0], bias1[0], bias1[0], bias1[0]};
      D1 = (f32x4){bias1[1], bias1[1], bias1[1], bias1[1]};
      MFMA(D0, h0al, W1h[0][0]); MFMA(D0, h0ah, W1l[0][0]); MFMA(D0, h0ah, W1h[0][0]);
      MFMA(D1, h0al, W1h[1][0]); MFMA(D1, h0ah, W1l[1][0]); MFMA(D1, h0ah, W1h[1][0]);
      MFMA(D0, h0bl, W1h[0][1]); MFMA(D0, h0bh, W1l[0][1]); MFMA(D0, h0bh, W1h[0][1]);
      MFMA(D1, h0bl, W1h[1][1]); MFMA(D1, h0bh, W1l[1][1]); MFMA(D1, h0bh, W1h[1][1]);
      MFMA(D0, h1al, W1h[0][2]); MFMA(D0, h1ah, W1l[0][2]); MFMA(D0, h1ah, W1h[0][2]);
      MFMA(D1, h1al, W1h[1][2]); MFMA(D1, h1ah, W1l[1][2]); MFMA(D1, h1ah, W1h[1][2]);
      MFMA(D0, h1bl, W1h[0][3]); MFMA(D0, h1bh, W1l[0][3]); MFMA(D0, h1bh, W1h[0][3]);
      MFMA(D1, h1bl, W1h[1][3]); MFMA(D1, h1bh, W1l[1][3]); MFMA(D1, h1bh, W1h[1][3]);
    }
  };

  // Combine phase for group g at time t: lanes layer==0 do L0(t) cells,
  // lanes layer==1 do L1(t-1) cells (from duplicated D rows).
  auto combinePh = [&](int g, int t, bool doL1,
                       const f32x4& A0, const f32x4& A1,
                       const f32x4& D0, const f32x4& D1,
                       float& ca, float& cb){
    const int wr0 = t & 1, wr1 = (t & 1) ^ 1;
    f32x4 P0, P1;
#pragma unroll
    for (int i = 0; i < 4; ++i){
      P0[i] = layer ? D0[i] : A0[i];
      P1[i] = layer ? D1[i] : A1[i];
    }
    f32x4 s0, s1;
    s0[0]=xor8(P0[0]); s0[1]=xor8(P0[1]); s0[2]=xor8(P0[2]); s0[3]=xor8(P0[3]);
    s1[0]=xor8(P1[0]); s1[1]=xor8(P1[1]); s1[2]=xor8(P1[2]); s1[3]=xor8(P1[3]);
    float gi_a = lo8 ? P0[0] : s0[2],  gi_b = lo8 ? P0[1] : s0[3];
    float gf_a = lo8 ? s0[0] : P0[2],  gf_b = lo8 ? s0[1] : P0[3];
    float gg_a = lo8 ? P1[0] : s1[2],  gg_b = lo8 ? P1[1] : s1[3];
    float go_a = lo8 ? s1[0] : P1[2],  go_b = lo8 ? s1[1] : P1[3];
    if (doL1 || layer == 0){
      ca = sigm(gf_a)*ca + sigm(gi_a)*ftanh(gg_a);
      float ha = sigm(go_a)*ftanh(ca);
      cb = sigm(gf_b)*cb + sigm(gi_b)*ftanh(gg_b);
      float hb = sigm(go_b)*ftanh(cb);
      unsigned hi2, lo2; split_pk(ha, hb, hi2, lo2);
      short* phi = layer ? &H1[wr1][0][0][0] : &H0[wr0][0][0][0];
      short* plo = layer ? &H1[wr1][1][0][0] : &H0[wr0][1][0][0];
      const int ra = (8*g + rwa)*88 + m;
      const int rb = (8*g + rwb)*88 + m;
      phi[ra] = (short)(hi2 & 0xFFFF);
      phi[rb] = (short)(hi2 >> 16);
      plo[ra] = (short)(lo2 & 0xFFFF);
      plo[rb] = (short)(lo2 >> 16);
    }
  };

  // final combine (L1(TT-1)) -> hout, lanes layer==1 only
  auto finalPh = [&](int g, const f32x4& D0, const f32x4& D1, float& ca, float& cb){
    f32x4 s0, s1;
    s0[0]=xor8(D0[0]); s0[1]=xor8(D0[1]); s0[2]=xor8(D0[2]); s0[3]=xor8(D0[3]);
    s1[0]=xor8(D1[0]); s1[1]=xor8(D1[1]); s1[2]=xor8(D1[2]); s1[3]=xor8(D1[3]);
    float gi_a = lo8 ? D0[0] : s0[2],  gi_b = lo8 ? D0[1] : s0[3];
    float gf_a = lo8 ? s0[0] : D0[2],  gf_b = lo8 ? s0[1] : D0[3];
    float gg_a = lo8 ? D1[0] : s1[2],  gg_b = lo8 ? D1[1] : s1[3];
    float go_a = lo8 ? s1[0] : D1[2],  go_b = lo8 ? s1[1] : D1[3];
    if (layer == 1){
      ca = sigm(gf_a)*ca + sigm(gi_a)*ftanh(gg_a);
      float ha = sigm(go_a)*ftanh(ca);
      cb = sigm(gf_b)*cb + sigm(gi_b)*ftanh(gg_b);
      float hb = sigm(go_b)*ftanh(cb);
      const int node_a = nA + 8*g + rwa;
      const int node_b = nA + 8*g + rwb;
      if (node_a < n) hout[(size_t)node_a*HH + m] = ha;
      if (node_b < n) hout[(size_t)node_b*HH + m] = hb;
    }
  };

  // ================= t = 0 =================
  mfmaPh(0, 0, 1, 0, true, false, aA0, aA1, dA0, dA1);
  __syncthreads();
  mfmaPh(1, 0, 1, 0, true, false, aB0, aB1, dB0, dB1);
  combinePh(0, 0, false, aA0, aA1, dA0, dA1, cAa, cAb);
  stageX(1);
  __syncthreads();

  // ================= main loop =================
  for (int t = 1; t < TT; ++t){
    const int bufx = t & 1, rd0 = (t & 1) ^ 1, rd1 = t & 1;
    // X(t): MFMA A(t) || combine B(t-1)
    mfmaPh(0, bufx, rd0, rd1, true, true, aA0, aA1, dA0, dA1);
    combinePh(1, t-1, (t-1) > 0, aB0, aB1, dB0, dB1, cBa, cBb);
    __syncthreads();
    // Y(t): MFMA B(t) || combine A(t), stage x(t+1)
    mfmaPh(1, bufx, rd0, rd1, true, true, aB0, aB1, dB0, dB1);
    combinePh(0, t, true, aA0, aA1, dA0, dA1, cAa, cAb);
    stageX(t + 1);
    __syncthreads();
  }

  // ================= epilogue: L1(TT-1) both groups =================
  // h0(TT-1) in buf 1, h1(TT-2) in buf 0
  mfmaPh(0, 0, 1, 0, false, true, aA0, aA1, dA0, dA1);
  combinePh(1, TT-1, true, aB0, aB1, dB0, dB1, cBa, cBb);
  __syncthreads();
  mfmaPh(1, 0, 1, 0, false, true, aB0, aB1, dB0, dB1);
  finalPh(0, dA0, dA1, cAa, cAb);
  finalPh(1, dB0, dB1, cBa, cBb);
}

// ---------------------------------------------------------------------------
// GCN support kernels (unchanged — not the bottleneck)
// ---------------------------------------------------------------------------
__global__ void k_count(const int* __restrict__ dst, int E, int* __restrict__ cnt)
{
  int e = blockIdx.x * blockDim.x + threadIdx.x;
  if (e < E) atomicAdd(&cnt[dst[e]], 1);
}

__global__ void k_scan_build(const int* __restrict__ cnt, int n,
                             int* __restrict__ offs, int* __restrict__ cursor,
                             float* __restrict__ dinv)
{
  __shared__ int part[1024];
  const int tid = threadIdx.x;
  const int per = (n + 1023) >> 10;
  const int base = tid * per;
  int s = 0;
  for (int i = 0; i < per; ++i) { int idx = base + i; if (idx < n) s += cnt[idx]; }
  part[tid] = s;
  __syncthreads();
  for (int off = 1; off < 1024; off <<= 1) {
    int v = 0;
    if (tid >= off) v = part[tid - off];
    __syncthreads();
    part[tid] += v;
    __syncthreads();
  }
  int run = part[tid] - s;
  for (int i = 0; i < per; ++i) {
    int idx = base + i;
    if (idx < n) {
      offs[idx] = run; cursor[idx] = run;
      int c = cnt[idx];
      dinv[idx] = 1.0f / sqrtf((float)(c + 1));
      run += c;
    }
  }
}

__global__ void k_fill(const int* __restrict__ src, const int* __restrict__ dst,
                       int E, int* __restrict__ cursor, int* __restrict__ csr)
{
  int e = blockIdx.x * blockDim.x + threadIdx.x;
  if (e < E) {
    int d = dst[e];
    int pos = atomicAdd(&cursor[d], 1);
    csr[pos] = src[e];
  }
}

template <int K, int M>
__global__ void k_xw(const float* __restrict__ A, const float* __restrict__ W,
                     float* __restrict__ out, int n)
{
  int idx = blockIdx.x * blockDim.x + threadIdx.x;
  int row = idx / M, col = idx % M;
  if (row >= n) return;
  const float* a = A + (size_t)row * K;
  float acc = 0.0f;
#pragma unroll
  for (int k = 0; k < K; ++k) acc = fmaf(a[k], W[k*M + col], acc);
  out[(size_t)row*M + col] = acc;
}

template <int FD>
__global__ void k_agg(const float* __restrict__ xw, const int* __restrict__ offs,
                      const int* __restrict__ cnt, const int* __restrict__ csr,
                      const float* __restrict__ dinv, const float* __restrict__ b,
                      float* __restrict__ out, int n)
{
  int gidx = blockIdx.x * blockDim.x + threadIdx.x;
  int node = gidx / FD, lane = gidx % FD;
  if (node >= n) return;
  const float di = dinv[node];
  float acc = xw[(size_t)node*FD + lane] * di * di;
  const int s0 = offs[node], e0 = s0 + cnt[node];
  for (int p = s0; p < e0; ++p) {
    int s = csr[p];
    acc = fmaf(xw[(size_t)s*FD + lane], dinv[s] * di, acc);
  }
  out[(size_t)node*FD + lane] = fmaxf(acc + b[lane], 0.0f);
}

__global__ void k_fc(const float* __restrict__ g2, const int* __restrict__ sid,
                     const float* __restrict__ fcW, const float* __restrict__ fcb,
                     float* __restrict__ out, int n)
{
  int i = blockIdx.x * blockDim.x + threadIdx.x;
  if (i >= n) return;
  const float* row = g2 + (size_t)sid[i] * GG2;
  float acc = fcb[0];
#pragma unroll
  for (int f = 0; f < GG2; ++f) acc = fmaf(row[f], fcW[f], acc);
  out[i] = acc;
}

// ---------------------------------------------------------------------------
extern "C" void kernel_launch(void* const* d_in, const int* in_sizes, int n_in,
                              void* d_out, int out_size, void* d_ws, size_t ws_size,
                              hipStream_t stream)
{
  const float* x    = (const float*)d_in[0];
  const int*   sid  = (const int*)  d_in[1];
  const int*   eidx = (const int*)  d_in[2];
  const float* Wih0 = (const float*)d_in[3];
  const float* Whh0 = (const float*)d_in[4];
  const float* bih0 = (const float*)d_in[5];
  const float* bhh0 = (const float*)d_in[6];
  const float* Wih1 = (const float*)d_in[7];
  const float* Whh1 = (const float*)d_in[8];
  const float* bih1 = (const float*)d_in[9];
  const float* bhh1 = (const float*)d_in[10];
  const float* g1W  = (const float*)d_in[11];
  const float* g1b  = (const float*)d_in[12];
  const float* g2W  = (const float*)d_in[13];
  const float* g2b  = (const float*)d_in[14];
  const float* fcW  = (const float*)d_in[15];
  const float* fcb  = (const float*)d_in[16];

  const int n = in_sizes[1];
  const int E = in_sizes[2] / 2;
  float* out = (float*)d_out;

  char* w = (char*)d_ws;
  auto carve = [&](size_t bytes) -> void* {
    void* p = (void*)w; w += (bytes + 255) & ~(size_t)255; return p;
  };
  float* hfin   = (float*)carve((size_t)n * HH * 4);
  int*   cnt    = (int*)  carve((size_t)n * 4);
  int*   offs   = (int*)  carve((size_t)n * 4);
  int*   cursor = (int*)  carve((size_t)n * 4);
  float* dinv   = (float*)carve((size_t)n * 4);
  int*   csr    = (int*)  carve((size_t)E * 4);
  float* xw1    = (float*)carve((size_t)n * GG1 * 4);
  float* g1     = (float*)carve((size_t)n * GG1 * 4);
  float* xw2    = (float*)carve((size_t)n * GG2 * 4);
  float* g2     = (float*)carve((size_t)n * GG2 * 4);

  const int* src = eidx;
  const int* dst = eidx + E;

  lstm_mfma<<<(n + NN - 1) / NN, 512, 0, stream>>>(x, Wih0, Whh0, bih0, bhh0,
                                                   Wih1, Whh1, bih1, bhh1, hfin, n);

  hipMemsetAsync(cnt, 0, (size_t)n * 4, stream);
  k_count<<<(E + 255) / 256, 256, 0, stream>>>(dst, E, cnt);
  k_scan_build<<<1, 1024, 0, stream>>>(cnt, n, offs, cursor, dinv);
  k_fill<<<(E + 255) / 256, 256, 0, stream>>>(src, dst, E, cursor, csr);

  k_xw<HH, GG1><<<((size_t)n * GG1 + 255) / 256, 256, 0, stream>>>(hfin, g1W, xw1, n);
  k_agg<GG1><<<((size_t)n * GG1 + 255) / 256, 256, 0, stream>>>(xw1, offs, cnt, csr, dinv, g1b, g1, n);

  k_xw<GG1, GG2><<<((size_t)n * GG2 + 255) / 256, 256, 0, stream>>>(g1, g2W, xw2, n);
  k_agg<GG2><<<((size_t)n * GG2 + 255) / 256, 256, 0, stream>>>(xw2, offs, cnt, csr, dinv, g2b, g2, n);

  k_fc<<<(n + 255) / 256, 256, 0, stream>>>(g2, sid, fcW, fcb, out, n);
}

// Round 10
// 723.327 us; speedup vs baseline: 1.3072x; 1.3072x over previous
//
#include <hip/hip_runtime.h>
#include <math.h>

#define TT 64
#define FF 32
#define HH 64
#define NN 16     // nodes per block
#define GG1 64
#define GG2 32

typedef float f32x4 __attribute__((ext_vector_type(4)));
typedef short bf16x8 __attribute__((ext_vector_type(8)));

__device__ __forceinline__ float fexp2(float x){ return __builtin_amdgcn_exp2f(x); }
__device__ __forceinline__ float frcp (float x){ return __builtin_amdgcn_rcpf(x); }
__device__ __forceinline__ float sigm (float v){ return frcp(1.0f + fexp2(-1.442695041f*v)); }
__device__ __forceinline__ float ftanh(float v){ return fmaf(-2.0f, frcp(1.0f + fexp2(2.885390082f*v)), 1.0f); }

// lane <-> lane^8 exchange within rows of 16 lanes (DPP row_ror:8, VALU pipe)
__device__ __forceinline__ float xor8(float v){
  int a = __builtin_bit_cast(int, v);
  int b = __builtin_amdgcn_update_dpp(0, a, 0x128, 0xF, 0xF, true);
  return __builtin_bit_cast(float, b);
}

__device__ __forceinline__ unsigned short bf16rn(float x){
  unsigned u = __builtin_bit_cast(unsigned, x);
  return (unsigned short)((u + 0x7FFFu + ((u >> 16) & 1u)) >> 16);
}
__device__ __forceinline__ void split2(float x, unsigned short& h, unsigned short& l){
  unsigned u = __builtin_bit_cast(unsigned, x);
  unsigned hr = (u + 0x7FFFu + ((u >> 16) & 1u)) & 0xFFFF0000u;
  h = (unsigned short)(hr >> 16);
  l = bf16rn(x - __builtin_bit_cast(float, hr));
}

#define PIN(v) asm volatile("" : "+v"(v))
#define MFMA(acc, a, b) (acc) = __builtin_amdgcn_mfma_f32_16x16x32_bf16((a), (b), (acc), 0, 0, 0)

__device__ __forceinline__ void wsplit(const float* p, bf16x8& hi, bf16x8& lo){
  float4 a = *(const float4*)p;
  float4 b = *(const float4*)(p + 4);
  unsigned short h, s;
  split2(a.x,h,s); hi[0]=(short)h; lo[0]=(short)s;
  split2(a.y,h,s); hi[1]=(short)h; lo[1]=(short)s;
  split2(a.z,h,s); hi[2]=(short)h; lo[2]=(short)s;
  split2(a.w,h,s); hi[3]=(short)h; lo[3]=(short)s;
  split2(b.x,h,s); hi[4]=(short)h; lo[4]=(short)s;
  split2(b.y,h,s); hi[5]=(short)h; lo[5]=(short)s;
  split2(b.z,h,s); hi[6]=(short)h; lo[6]=(short)s;
  split2(b.w,h,s); hi[7]=(short)h; lo[7]=(short)s;
}

// ---------------------------------------------------------------------------
// Fused 2-layer LSTM on MFMA with bf16 hi/lo emulated-fp32 (3-pass),
// in-register gate combine via DPP row_ror:8 (round-8 structure), with
// SPLIT ACCUMULATOR CHAINS: each gate tile uses 2 independent MFMA chains
// (L0: x-chain || h-chain; L1: h0-chain || h1-chain) merged by one f32x4 add
// before the combine — 8 independent chains/wave halves the acc-drain
// latency the VALU combine waits on. One barrier per timestep.
// ---------------------------------------------------------------------------
__global__ __launch_bounds__(512, 2)
void lstm_mfma(const float* __restrict__ x,
    const float* __restrict__ Wih0, const float* __restrict__ Whh0,
    const float* __restrict__ bih0, const float* __restrict__ bhh0,
    const float* __restrict__ Wih1, const float* __restrict__ Whh1,
    const float* __restrict__ bih1, const float* __restrict__ bhh1,
    float* __restrict__ hout, int n)
{
  const int tid = threadIdx.x;
  const int w   = tid >> 6;     // wave 0..7
  const int l   = tid & 63;
  const int lr  = l & 15;       // A row (node) / B,D col-slot
  const int lg  = l >> 4;       // k-group 0..3
  const int nA  = blockIdx.x * NN;
  int avail = n - nA; if (avail > NN) avail = NN;

  __shared__ short Ax[2][2][16][40];   // [buf][hi/lo][node][f]   80B rows
  __shared__ short H0[2][2][16][88];   // [buf][hi/lo][node][m]  176B rows
  __shared__ short H1[2][2][16][88];

  // ---- gate-col mapping: tile0 = (i|f), tile1 = (g|o) for m = 8w+(lr&7) ----
  const int jm   = lr & 7;
  const bool lo8 = (lr < 8);
  const int col0 = lo8 ? (8*w + jm) : (64  + 8*w + jm);       // i | f
  const int col1 = lo8 ? (128 + 8*w + jm) : (192 + 8*w + jm); // g | o

  // ---- weights -> split register fragments ----
  bf16x8 W0h[2][3], W0l[2][3], W1h[2][4], W1l[2][4];
  float bias0[2], bias1[2];
#pragma unroll
  for (int h = 0; h < 2; ++h){
    const int col = h ? col1 : col0;
    wsplit(Wih0 + col*FF + 8*lg,      W0h[h][0], W0l[h][0]);  // x   k 0..31
    wsplit(Whh0 + col*HH + 8*lg,      W0h[h][1], W0l[h][1]);  // h0  k 0..31
    wsplit(Whh0 + col*HH + 32 + 8*lg, W0h[h][2], W0l[h][2]);  // h0  k 32..63
    wsplit(Wih1 + col*HH + 8*lg,      W1h[h][0], W1l[h][0]);
    wsplit(Wih1 + col*HH + 32 + 8*lg, W1h[h][1], W1l[h][1]);
    wsplit(Whh1 + col*HH + 8*lg,      W1h[h][2], W1l[h][2]);
    wsplit(Whh1 + col*HH + 32 + 8*lg, W1h[h][3], W1l[h][3]);
    bias0[h] = bih0[col] + bhh0[col];
    bias1[h] = bih1[col] + bhh1[col];
  }
#pragma unroll
  for (int h = 0; h < 2; ++h){
#pragma unroll
    for (int k = 0; k < 3; ++k){ PIN(W0h[h][k]); PIN(W0l[h][k]); }
#pragma unroll
    for (int k = 0; k < 4; ++k){ PIN(W1h[h][k]); PIN(W1l[h][k]); }
  }

  // ---- zero h planes; stage x(0) ----
  {
    short* p0 = &H0[0][0][0][0];
    short* p1 = &H1[0][0][0][0];
    for (int i = tid; i < 2*2*16*88; i += 512){ p0[i] = 0; p1[i] = 0; }
    const int xnd = tid >> 5, xf = tid & 31;
    float v = (xnd < avail) ? x[((size_t)(nA+xnd)*TT + 0)*FF + xf] : 0.0f;
    unsigned short hh, hl; split2(v, hh, hl);
    Ax[0][0][xnd][xf] = (short)hh;
    Ax[0][1][xnd][xf] = (short)hl;
  }
  const int na = 4*lg + (lo8 ? 0 : 2);
  const int nb = na + 1;
  const int m  = 8*w + jm;
  float c0a = 0.0f, c0b = 0.0f, c1a = 0.0f, c1b = 0.0f;
  __syncthreads();

  for (int t = 0; t < TT; ++t){
    const int rd0 = (t & 1) ^ 1;   // h0(t-1)
    const int wr0 =  t & 1;        // h0(t)
    const int rd1 =  t & 1;        // h1(t-2)
    const int wr1 = (t & 1) ^ 1;   // h1(t-1)

    // issue x(t+1) load early (consumed after MFMAs)
    const int xnd = tid >> 5, xf = tid & 31;
    const int tp = t + 1;
    float xv = 0.0f;
    if (tp < TT && xnd < avail) xv = x[((size_t)(nA+xnd)*TT + tp)*FF + xf];

    // ---- A fragments ----
    bf16x8 axh  = *(const bf16x8*)&Ax[t&1][0][lr][8*lg];
    bf16x8 axl  = *(const bf16x8*)&Ax[t&1][1][lr][8*lg];
    bf16x8 h0ah = *(const bf16x8*)&H0[rd0][0][lr][8*lg];
    bf16x8 h0al = *(const bf16x8*)&H0[rd0][1][lr][8*lg];
    bf16x8 h0bh = *(const bf16x8*)&H0[rd0][0][lr][32+8*lg];
    bf16x8 h0bl = *(const bf16x8*)&H0[rd0][1][lr][32+8*lg];

    // ---- L0 gates(t): 2 tiles x 2 independent chains (x || h) ----
    f32x4 ax0 = {bias0[0], bias0[0], bias0[0], bias0[0]};
    f32x4 ax1 = {bias0[1], bias0[1], bias0[1], bias0[1]};
    f32x4 ah0 = {0.f,0.f,0.f,0.f}, ah1 = {0.f,0.f,0.f,0.f};
    MFMA(ax0, axl,  W0h[0][0]); MFMA(ax0, axh,  W0l[0][0]); MFMA(ax0, axh,  W0h[0][0]);
    MFMA(ax1, axl,  W0h[1][0]); MFMA(ax1, axh,  W0l[1][0]); MFMA(ax1, axh,  W0h[1][0]);
    MFMA(ah0, h0al, W0h[0][1]); MFMA(ah0, h0ah, W0l[0][1]); MFMA(ah0, h0ah, W0h[0][1]);
    MFMA(ah1, h0al, W0h[1][1]); MFMA(ah1, h0ah, W0l[1][1]); MFMA(ah1, h0ah, W0h[1][1]);
    MFMA(ah0, h0bl, W0h[0][2]); MFMA(ah0, h0bh, W0l[0][2]); MFMA(ah0, h0bh, W0h[0][2]);
    MFMA(ah1, h0bl, W0h[1][2]); MFMA(ah1, h0bh, W0l[1][2]); MFMA(ah1, h0bh, W0h[1][2]);

    // ---- L1 gates(t-1): 2 tiles x 2 independent chains (h0 || h1) ----
    f32x4 ap0, ap1, aq0, aq1;
    if (t > 0){
      bf16x8 h1ah = *(const bf16x8*)&H1[rd1][0][lr][8*lg];
      bf16x8 h1al = *(const bf16x8*)&H1[rd1][1][lr][8*lg];
      bf16x8 h1bh = *(const bf16x8*)&H1[rd1][0][lr][32+8*lg];
      bf16x8 h1bl = *(const bf16x8*)&H1[rd1][1][lr][32+8*lg];
      ap0 = (f32x4){bias1[0], bias1[0], bias1[0], bias1[0]};
      ap1 = (f32x4){bias1[1], bias1[1], bias1[1], bias1[1]};
      aq0 = (f32x4){0.f,0.f,0.f,0.f};
      aq1 = (f32x4){0.f,0.f,0.f,0.f};
      MFMA(ap0, h0al, W1h[0][0]); MFMA(ap0, h0ah, W1l[0][0]); MFMA(ap0, h0ah, W1h[0][0]);
      MFMA(ap1, h0al, W1h[1][0]); MFMA(ap1, h0ah, W1l[1][0]); MFMA(ap1, h0ah, W1h[1][0]);
      MFMA(ap0, h0bl, W1h[0][1]); MFMA(ap0, h0bh, W1l[0][1]); MFMA(ap0, h0bh, W1h[0][1]);
      MFMA(ap1, h0bl, W1h[1][1]); MFMA(ap1, h0bh, W1l[1][1]); MFMA(ap1, h0bh, W1h[1][1]);
      MFMA(aq0, h1al, W1h[0][2]); MFMA(aq0, h1ah, W1l[0][2]); MFMA(aq0, h1ah, W1h[0][2]);
      MFMA(aq1, h1al, W1h[1][2]); MFMA(aq1, h1ah, W1l[1][2]); MFMA(aq1, h1ah, W1h[1][2]);
      MFMA(aq0, h1bl, W1h[0][3]); MFMA(aq0, h1bh, W1l[0][3]); MFMA(aq0, h1bh, W1h[0][3]);
      MFMA(aq1, h1bl, W1h[1][3]); MFMA(aq1, h1bh, W1l[1][3]); MFMA(aq1, h1bh, W1h[1][3]);
    }

    // stage x(t+1) split (hidden under MFMA latency)
    if (tp < TT){
      unsigned short hh, hl; split2(xv, hh, hl);
      Ax[tp&1][0][xnd][xf] = (short)hh;
      Ax[tp&1][1][xnd][xf] = (short)hl;
    }

    // ---- in-register combine L0(t) ----
    {
      f32x4 acc0 = ax0 + ah0;
      f32x4 acc1 = ax1 + ah1;
      f32x4 s0, s1;
      s0[0]=xor8(acc0[0]); s0[1]=xor8(acc0[1]); s0[2]=xor8(acc0[2]); s0[3]=xor8(acc0[3]);
      s1[0]=xor8(acc1[0]); s1[1]=xor8(acc1[1]); s1[2]=xor8(acc1[2]); s1[3]=xor8(acc1[3]);
      float gi_a = lo8 ? acc0[0] : s0[2],  gi_b = lo8 ? acc0[1] : s0[3];
      float gf_a = lo8 ? s0[0] : acc0[2],  gf_b = lo8 ? s0[1] : acc0[3];
      float gg_a = lo8 ? acc1[0] : s1[2],  gg_b = lo8 ? acc1[1] : s1[3];
      float go_a = lo8 ? s1[0] : acc1[2],  go_b = lo8 ? s1[1] : acc1[3];
      c0a = sigm(gf_a)*c0a + sigm(gi_a)*ftanh(gg_a);
      float ha = sigm(go_a)*ftanh(c0a);
      c0b = sigm(gf_b)*c0b + sigm(gi_b)*ftanh(gg_b);
      float hb = sigm(go_b)*ftanh(c0b);
      unsigned short hh, hl;
      split2(ha, hh, hl); H0[wr0][0][na][m] = (short)hh; H0[wr0][1][na][m] = (short)hl;
      split2(hb, hh, hl); H0[wr0][0][nb][m] = (short)hh; H0[wr0][1][nb][m] = (short)hl;
    }
    // ---- in-register combine L1(t-1) ----
    if (t > 0){
      f32x4 acd0 = ap0 + aq0;
      f32x4 acd1 = ap1 + aq1;
      f32x4 s0, s1;
      s0[0]=xor8(acd0[0]); s0[1]=xor8(acd0[1]); s0[2]=xor8(acd0[2]); s0[3]=xor8(acd0[3]);
      s1[0]=xor8(acd1[0]); s1[1]=xor8(acd1[1]); s1[2]=xor8(acd1[2]); s1[3]=xor8(acd1[3]);
      float gi_a = lo8 ? acd0[0] : s0[2],  gi_b = lo8 ? acd0[1] : s0[3];
      float gf_a = lo8 ? s0[0] : acd0[2],  gf_b = lo8 ? s0[1] : acd0[3];
      float gg_a = lo8 ? acd1[0] : s1[2],  gg_b = lo8 ? acd1[1] : s1[3];
      float go_a = lo8 ? s1[0] : acd1[2],  go_b = lo8 ? s1[1] : acd1[3];
      c1a = sigm(gf_a)*c1a + sigm(gi_a)*ftanh(gg_a);
      float ha = sigm(go_a)*ftanh(c1a);
      c1b = sigm(gf_b)*c1b + sigm(gi_b)*ftanh(gg_b);
      float hb = sigm(go_b)*ftanh(c1b);
      unsigned short hh, hl;
      split2(ha, hh, hl); H1[wr1][0][na][m] = (short)hh; H1[wr1][1][na][m] = (short)hl;
      split2(hb, hh, hl); H1[wr1][0][nb][m] = (short)hh; H1[wr1][1][nb][m] = (short)hl;
    }
    __syncthreads();   // single barrier per timestep
  }

  // ---- epilogue: L1 gates(TT-1) + combine -> hout ----
  {
    const int rd0 = (TT-1) & 1;      // h0(TT-1)
    const int rd1 =  TT & 1;         // h1(TT-2)
    bf16x8 h0ah = *(const bf16x8*)&H0[rd0][0][lr][8*lg];
    bf16x8 h0al = *(const bf16x8*)&H0[rd0][1][lr][8*lg];
    bf16x8 h0bh = *(const bf16x8*)&H0[rd0][0][lr][32+8*lg];
    bf16x8 h0bl = *(const bf16x8*)&H0[rd0][1][lr][32+8*lg];
    bf16x8 h1ah = *(const bf16x8*)&H1[rd1][0][lr][8*lg];
    bf16x8 h1al = *(const bf16x8*)&H1[rd1][1][lr][8*lg];
    bf16x8 h1bh = *(const bf16x8*)&H1[rd1][0][lr][32+8*lg];
    bf16x8 h1bl = *(const bf16x8*)&H1[rd1][1][lr][32+8*lg];
    f32x4 ap0 = {bias1[0], bias1[0], bias1[0], bias1[0]};
    f32x4 ap1 = {bias1[1], bias1[1], bias1[1], bias1[1]};
    f32x4 aq0 = {0.f,0.f,0.f,0.f}, aq1 = {0.f,0.f,0.f,0.f};
    MFMA(ap0, h0al, W1h[0][0]); MFMA(ap0, h0ah, W1l[0][0]); MFMA(ap0, h0ah, W1h[0][0]);
    MFMA(ap1, h0al, W1h[1][0]); MFMA(ap1, h0ah, W1l[1][0]); MFMA(ap1, h0ah, W1h[1][0]);
    MFMA(ap0, h0bl, W1h[0][1]); MFMA(ap0, h0bh, W1l[0][1]); MFMA(ap0, h0bh, W1h[0][1]);
    MFMA(ap1, h0bl, W1h[1][1]); MFMA(ap1, h0bh, W1l[1][1]); MFMA(ap1, h0bh, W1h[1][1]);
    MFMA(aq0, h1al, W1h[0][2]); MFMA(aq0, h1ah, W1l[0][2]); MFMA(aq0, h1ah, W1h[0][2]);
    MFMA(aq1, h1al, W1h[1][2]); MFMA(aq1, h1ah, W1l[1][2]); MFMA(aq1, h1ah, W1h[1][2]);
    MFMA(aq0, h1bl, W1h[0][3]); MFMA(aq0, h1bh, W1l[0][3]); MFMA(aq0, h1bh, W1h[0][3]);
    MFMA(aq1, h1bl, W1h[1][3]); MFMA(aq1, h1bh, W1l[1][3]); MFMA(aq1, h1bh, W1h[1][3]);

    f32x4 acd0 = ap0 + aq0;
    f32x4 acd1 = ap1 + aq1;
    f32x4 s0, s1;
    s0[0]=xor8(acd0[0]); s0[1]=xor8(acd0[1]); s0[2]=xor8(acd0[2]); s0[3]=xor8(acd0[3]);
    s1[0]=xor8(acd1[0]); s1[1]=xor8(acd1[1]); s1[2]=xor8(acd1[2]); s1[3]=xor8(acd1[3]);
    float gi_a = lo8 ? acd0[0] : s0[2],  gi_b = lo8 ? acd0[1] : s0[3];
    float gf_a = lo8 ? s0[0] : acd0[2],  gf_b = lo8 ? s0[1] : acd0[3];
    float gg_a = lo8 ? acd1[0] : s1[2],  gg_b = lo8 ? acd1[1] : s1[3];
    float go_a = lo8 ? s1[0] : acd1[2],  go_b = lo8 ? s1[1] : acd1[3];
    c1a = sigm(gf_a)*c1a + sigm(gi_a)*ftanh(gg_a);
    float ha = sigm(go_a)*ftanh(c1a);
    c1b = sigm(gf_b)*c1b + sigm(gi_b)*ftanh(gg_b);
    float hb = sigm(go_b)*ftanh(c1b);
    if (nA + na < n) hout[(size_t)(nA+na)*HH + m] = ha;
    if (nA + nb < n) hout[(size_t)(nA+nb)*HH + m] = hb;
  }
}

// ---------------------------------------------------------------------------
// GCN support kernels
// ---------------------------------------------------------------------------
__global__ void k_count(const int* __restrict__ dst, int E, int* __restrict__ cnt)
{
  int e = blockIdx.x * blockDim.x + threadIdx.x;
  if (e < E) atomicAdd(&cnt[dst[e]], 1);
}

__global__ void k_scan_build(const int* __restrict__ cnt, int n,
                             int* __restrict__ offs, int* __restrict__ cursor,
                             float* __restrict__ dinv)
{
  __shared__ int part[1024];
  const int tid = threadIdx.x;
  const int per = (n + 1023) >> 10;
  const int base = tid * per;
  int s = 0;
  for (int i = 0; i < per; ++i) { int idx = base + i; if (idx < n) s += cnt[idx]; }
  part[tid] = s;
  __syncthreads();
  for (int off = 1; off < 1024; off <<= 1) {
    int v = 0;
    if (tid >= off) v = part[tid - off];
    __syncthreads();
    part[tid] += v;
    __syncthreads();
  }
  int run = part[tid] - s;
  for (int i = 0; i < per; ++i) {
    int idx = base + i;
    if (idx < n) {
      offs[idx] = run; cursor[idx] = run;
      int c = cnt[idx];
      dinv[idx] = 1.0f / sqrtf((float)(c + 1));
      run += c;
    }
  }
}

__global__ void k_fill(const int* __restrict__ src, const int* __restrict__ dst,
                       int E, int* __restrict__ cursor, int* __restrict__ csr)
{
  int e = blockIdx.x * blockDim.x + threadIdx.x;
  if (e < E) {
    int d = dst[e];
    int pos = atomicAdd(&cursor[d], 1);
    csr[pos] = src[e];
  }
}

template <int K, int M>
__global__ void k_xw(const float* __restrict__ A, const float* __restrict__ W,
                     float* __restrict__ out, int n)
{
  int idx = blockIdx.x * blockDim.x + threadIdx.x;
  int row = idx / M, col = idx % M;
  if (row >= n) return;
  const float* a = A + (size_t)row * K;
  float acc = 0.0f;
#pragma unroll
  for (int k = 0; k < K; ++k) acc = fmaf(a[k], W[k*M + col], acc);
  out[(size_t)row*M + col] = acc;
}

// CSR aggregate for layer1 (FD=64) + bias/relu, FUSED with xw2 = g1 @ W2.
// Block = 256 threads = 4 nodes x 64 lanes.
__global__ void k_agg_x2(const float* __restrict__ xw, const int* __restrict__ offs,
                         const int* __restrict__ cnt, const int* __restrict__ csr,
                         const float* __restrict__ dinv, const float* __restrict__ b,
                         const float* __restrict__ W2,
                         float* __restrict__ g1out, float* __restrict__ xw2out, int n)
{
  __shared__ float sg[4][GG1];
  const int nd   = threadIdx.x >> 6;
  const int lane = threadIdx.x & 63;
  const int node = blockIdx.x * 4 + nd;
  if (node < n) {
    const float di = dinv[node];
    float acc = xw[(size_t)node*GG1 + lane] * di * di;
    const int s0 = offs[node], e0 = s0 + cnt[node];
    for (int p = s0; p < e0; ++p) {
      int s = csr[p];
      acc = fmaf(xw[(size_t)s*GG1 + lane], dinv[s] * di, acc);
    }
    float val = fmaxf(acc + b[lane], 0.0f);
    g1out[(size_t)node*GG1 + lane] = val;
    sg[nd][lane] = val;
  }
  __syncthreads();
  if (node < n && lane < GG2) {
    float a2 = 0.0f;
#pragma unroll
    for (int k = 0; k < GG1; ++k) a2 = fmaf(sg[nd][k], W2[k*GG2 + lane], a2);
    xw2out[(size_t)node*GG2 + lane] = a2;
  }
}

template <int FD>
__global__ void k_agg(const float* __restrict__ xw, const int* __restrict__ offs,
                      const int* __restrict__ cnt, const int* __restrict__ csr,
                      const float* __restrict__ dinv, const float* __restrict__ b,
                      float* __restrict__ out, int n)
{
  int gidx = blockIdx.x * blockDim.x + threadIdx.x;
  int node = gidx / FD, lane = gidx % FD;
  if (node >= n) return;
  const float di = dinv[node];
  float acc = xw[(size_t)node*FD + lane] * di * di;
  const int s0 = offs[node], e0 = s0 + cnt[node];
  for (int p = s0; p < e0; ++p) {
    int s = csr[p];
    acc = fmaf(xw[(size_t)s*FD + lane], dinv[s] * di, acc);
  }
  out[(size_t)node*FD + lane] = fmaxf(acc + b[lane], 0.0f);
}

__global__ void k_fc(const float* __restrict__ g2, const int* __restrict__ sid,
                     const float* __restrict__ fcW, const float* __restrict__ fcb,
                     float* __restrict__ out, int n)
{
  int i = blockIdx.x * blockDim.x + threadIdx.x;
  if (i >= n) return;
  const float* row = g2 + (size_t)sid[i] * GG2;
  float acc = fcb[0];
#pragma unroll
  for (int f = 0; f < GG2; ++f) acc = fmaf(row[f], fcW[f], acc);
  out[i] = acc;
}

// ---------------------------------------------------------------------------
extern "C" void kernel_launch(void* const* d_in, const int* in_sizes, int n_in,
                              void* d_out, int out_size, void* d_ws, size_t ws_size,
                              hipStream_t stream)
{
  const float* x    = (const float*)d_in[0];
  const int*   sid  = (const int*)  d_in[1];
  const int*   eidx = (const int*)  d_in[2];
  const float* Wih0 = (const float*)d_in[3];
  const float* Whh0 = (const float*)d_in[4];
  const float* bih0 = (const float*)d_in[5];
  const float* bhh0 = (const float*)d_in[6];
  const float* Wih1 = (const float*)d_in[7];
  const float* Whh1 = (const float*)d_in[8];
  const float* bih1 = (const float*)d_in[9];
  const float* bhh1 = (const float*)d_in[10];
  const float* g1W  = (const float*)d_in[11];
  const float* g1b  = (const float*)d_in[12];
  const float* g2W  = (const float*)d_in[13];
  const float* g2b  = (const float*)d_in[14];
  const float* fcW  = (const float*)d_in[15];
  const float* fcb  = (const float*)d_in[16];

  const int n = in_sizes[1];
  const int E = in_sizes[2] / 2;
  float* out = (float*)d_out;

  char* w = (char*)d_ws;
  auto carve = [&](size_t bytes) -> void* {
    void* p = (void*)w; w += (bytes + 255) & ~(size_t)255; return p;
  };
  float* hfin   = (float*)carve((size_t)n * HH * 4);
  int*   cnt    = (int*)  carve((size_t)n * 4);
  int*   offs   = (int*)  carve((size_t)n * 4);
  int*   cursor = (int*)  carve((size_t)n * 4);
  float* dinv   = (float*)carve((size_t)n * 4);
  int*   csr    = (int*)  carve((size_t)E * 4);
  float* xw1    = (float*)carve((size_t)n * GG1 * 4);
  float* g1     = (float*)carve((size_t)n * GG1 * 4);
  float* xw2    = (float*)carve((size_t)n * GG2 * 4);
  float* g2     = (float*)carve((size_t)n * GG2 * 4);

  const int* src = eidx;
  const int* dst = eidx + E;

  lstm_mfma<<<(n + NN - 1) / NN, 512, 0, stream>>>(x, Wih0, Whh0, bih0, bhh0,
                                                   Wih1, Whh1, bih1, bhh1, hfin, n);

  hipMemsetAsync(cnt, 0, (size_t)n * 4, stream);
  k_count<<<(E + 255) / 256, 256, 0, stream>>>(dst, E, cnt);
  k_scan_build<<<1, 1024, 0, stream>>>(cnt, n, offs, cursor, dinv);
  k_fill<<<(E + 255) / 256, 256, 0, stream>>>(src, dst, E, cursor, csr);

  k_xw<HH, GG1><<<((size_t)n * GG1 + 255) / 256, 256, 0, stream>>>(hfin, g1W, xw1, n);
  k_agg_x2<<<(n + 3) / 4, 256, 0, stream>>>(xw1, offs, cnt, csr, dinv, g1b, g2W, g1, xw2, n);

  k_agg<GG2><<<((size_t)n * GG2 + 255) / 256, 256, 0, stream>>>(xw2, offs, cnt, csr, dinv, g2b, g2, n);

  k_fc<<<(n + 255) / 256, 256, 0, stream>>>(g2, sid, fcW, fcb, out, n);
}

// Round 11
// 696.469 us; speedup vs baseline: 1.3576x; 1.0386x over previous
//
#include <hip/hip_runtime.h>
#include <math.h>

#define TT 64
#define FF 32
#define HH 64
#define NN 16     // nodes per block
#define GG1 64
#define GG2 32

typedef float f32x4 __attribute__((ext_vector_type(4)));
typedef short bf16x8 __attribute__((ext_vector_type(8)));

__device__ __forceinline__ float fexp2(float x){ return __builtin_amdgcn_exp2f(x); }
__device__ __forceinline__ float frcp (float x){ return __builtin_amdgcn_rcpf(x); }
#define L2E 1.442695041f
// bias-folded nonlinearities: nb = -L2E*b, b2 = 2*L2E*b (precomputed per lane)
__device__ __forceinline__ float sigm_nb(float v, float nb){
  return frcp(1.0f + fexp2(fmaf(v, -L2E, nb)));
}
__device__ __forceinline__ float tanh_b(float v, float b2){
  return fmaf(-2.0f, frcp(1.0f + fexp2(fmaf(v, 2.0f*L2E, b2))), 1.0f);
}
__device__ __forceinline__ float tanh0(float v){
  return fmaf(-2.0f, frcp(1.0f + fexp2(2.0f*L2E*v)), 1.0f);
}

// lane <-> lane^8 exchange within rows of 16 lanes (DPP row_ror:8, VALU pipe)
__device__ __forceinline__ float xor8(float v){
  int a = __builtin_bit_cast(int, v);
  int b = __builtin_amdgcn_update_dpp(0, a, 0x128, 0xF, 0xF, true);
  return __builtin_bit_cast(float, b);
}

__device__ __forceinline__ unsigned short bf16rn(float x){
  unsigned u = __builtin_bit_cast(unsigned, x);
  return (unsigned short)((u + 0x7FFFu + ((u >> 16) & 1u)) >> 16);
}
__device__ __forceinline__ void split2(float x, unsigned short& h, unsigned short& l){
  unsigned u = __builtin_bit_cast(unsigned, x);
  unsigned hr = (u + 0x7FFFu + ((u >> 16) & 1u)) & 0xFFFF0000u;
  h = (unsigned short)(hr >> 16);
  l = bf16rn(x - __builtin_bit_cast(float, hr));
}
// packed split of 2 values via v_cvt_pk_bf16_f32 (HW RNE, validated round 9)
__device__ __forceinline__ void split_pk(float a, float b, unsigned& hi2, unsigned& lo2){
  asm("v_cvt_pk_bf16_f32 %0, %1, %2" : "=v"(hi2) : "v"(a), "v"(b));
  float ha = __builtin_bit_cast(float, hi2 << 16);
  float hb = __builtin_bit_cast(float, hi2 & 0xFFFF0000u);
  float la = a - ha, lb = b - hb;
  asm("v_cvt_pk_bf16_f32 %0, %1, %2" : "=v"(lo2) : "v"(la), "v"(lb));
}

#define PIN(v) asm volatile("" : "+v"(v))
#define MFMA(acc, a, b) (acc) = __builtin_amdgcn_mfma_f32_16x16x32_bf16((a), (b), (acc), 0, 0, 0)

__device__ __forceinline__ void wsplit(const float* p, bf16x8& hi, bf16x8& lo){
  float4 a = *(const float4*)p;
  float4 b = *(const float4*)(p + 4);
  unsigned short h, s;
  split2(a.x,h,s); hi[0]=(short)h; lo[0]=(short)s;
  split2(a.y,h,s); hi[1]=(short)h; lo[1]=(short)s;
  split2(a.z,h,s); hi[2]=(short)h; lo[2]=(short)s;
  split2(a.w,h,s); hi[3]=(short)h; lo[3]=(short)s;
  split2(b.x,h,s); hi[4]=(short)h; lo[4]=(short)s;
  split2(b.y,h,s); hi[5]=(short)h; lo[5]=(short)s;
  split2(b.z,h,s); hi[6]=(short)h; lo[6]=(short)s;
  split2(b.w,h,s); hi[7]=(short)h; lo[7]=(short)s;
}

// ---------------------------------------------------------------------------
// Fused 2-layer LSTM on MFMA, bf16 hi/lo emulated-fp32 (3-pass), in-register
// gate combine via DPP row_ror:8 (round-8 structure). Round-11 deltas:
//  * MFMA chains start from a shared zero vector (no per-t acc-init movs);
//    gate biases folded into the nonlinearity fmafs (pre-scaled constants).
//  * H-state writes use v_cvt_pk_bf16_f32 pair-split.
//  * s_setprio(1) around the MFMA cluster (T5) for 2-wave pipe overlap.
// One barrier per timestep.
// ---------------------------------------------------------------------------
__global__ __launch_bounds__(512, 2)
void lstm_mfma(const float* __restrict__ x,
    const float* __restrict__ Wih0, const float* __restrict__ Whh0,
    const float* __restrict__ bih0, const float* __restrict__ bhh0,
    const float* __restrict__ Wih1, const float* __restrict__ Whh1,
    const float* __restrict__ bih1, const float* __restrict__ bhh1,
    float* __restrict__ hout, int n)
{
  const int tid = threadIdx.x;
  const int w   = tid >> 6;     // wave 0..7
  const int l   = tid & 63;
  const int lr  = l & 15;       // A row (node) / B,D col-slot
  const int lg  = l >> 4;       // k-group 0..3
  const int nA  = blockIdx.x * NN;
  int avail = n - nA; if (avail > NN) avail = NN;

  __shared__ short Ax[2][2][16][40];   // [buf][hi/lo][node][f]   80B rows
  __shared__ short H0[2][2][16][88];   // [buf][hi/lo][node][m]  176B rows
  __shared__ short H1[2][2][16][88];

  // ---- gate-col mapping: tile0 = (i|f), tile1 = (g|o) for m = 8w+(lr&7) ----
  const int jm   = lr & 7;
  const bool lo8 = (lr < 8);
  const int col0 = lo8 ? (8*w + jm) : (64  + 8*w + jm);       // i | f
  const int col1 = lo8 ? (128 + 8*w + jm) : (192 + 8*w + jm); // g | o

  // ---- weights -> split register fragments ----
  bf16x8 W0h[2][3], W0l[2][3], W1h[2][4], W1l[2][4];
#pragma unroll
  for (int h = 0; h < 2; ++h){
    const int col = h ? col1 : col0;
    wsplit(Wih0 + col*FF + 8*lg,      W0h[h][0], W0l[h][0]);  // x   k 0..31
    wsplit(Whh0 + col*HH + 8*lg,      W0h[h][1], W0l[h][1]);  // h0  k 0..31
    wsplit(Whh0 + col*HH + 32 + 8*lg, W0h[h][2], W0l[h][2]);  // h0  k 32..63
    wsplit(Wih1 + col*HH + 8*lg,      W1h[h][0], W1l[h][0]);
    wsplit(Wih1 + col*HH + 32 + 8*lg, W1h[h][1], W1l[h][1]);
    wsplit(Whh1 + col*HH + 8*lg,      W1h[h][2], W1l[h][2]);
    wsplit(Whh1 + col*HH + 32 + 8*lg, W1h[h][3], W1l[h][3]);
  }
#pragma unroll
  for (int h = 0; h < 2; ++h){
#pragma unroll
    for (int k = 0; k < 3; ++k){ PIN(W0h[h][k]); PIN(W0l[h][k]); }
#pragma unroll
    for (int k = 0; k < 4; ++k){ PIN(W1h[h][k]); PIN(W1l[h][k]); }
  }

  // ---- per-lane pre-scaled gate biases for column m = 8w+jm ----
  const int m  = 8*w + jm;
  const float nb_i0 = -L2E      * (bih0[m      ] + bhh0[m      ]);
  const float nb_f0 = -L2E      * (bih0[m +  64] + bhh0[m +  64]);
  const float b2_g0 =  2.0f*L2E * (bih0[m + 128] + bhh0[m + 128]);
  const float nb_o0 = -L2E      * (bih0[m + 192] + bhh0[m + 192]);
  const float nb_i1 = -L2E      * (bih1[m      ] + bhh1[m      ]);
  const float nb_f1 = -L2E      * (bih1[m +  64] + bhh1[m +  64]);
  const float b2_g1 =  2.0f*L2E * (bih1[m + 128] + bhh1[m + 128]);
  const float nb_o1 = -L2E      * (bih1[m + 192] + bhh1[m + 192]);

  // ---- zero h planes; stage x(0) ----
  {
    short* p0 = &H0[0][0][0][0];
    short* p1 = &H1[0][0][0][0];
    for (int i = tid; i < 2*2*16*88; i += 512){ p0[i] = 0; p1[i] = 0; }
    const int xnd = tid >> 5, xf = tid & 31;
    float v = (xnd < avail) ? x[((size_t)(nA+xnd)*TT + 0)*FF + xf] : 0.0f;
    unsigned short hh, hl; split2(v, hh, hl);
    Ax[0][0][xnd][xf] = (short)hh;
    Ax[0][1][xnd][xf] = (short)hl;
  }
  const int na = 4*lg + (lo8 ? 0 : 2);
  const int nb = na + 1;
  float c0a = 0.0f, c0b = 0.0f, c1a = 0.0f, c1b = 0.0f;
  const f32x4 Z = {0.f, 0.f, 0.f, 0.f};   // shared loop-invariant C-init
  __syncthreads();

  for (int t = 0; t < TT; ++t){
    const int rd0 = (t & 1) ^ 1;   // h0(t-1)
    const int wr0 =  t & 1;        // h0(t)
    const int rd1 =  t & 1;        // h1(t-2)
    const int wr1 = (t & 1) ^ 1;   // h1(t-1)

    // issue x(t+1) load early (consumed after MFMAs)
    const int xnd = tid >> 5, xf = tid & 31;
    const int tp = t + 1;
    float xv = 0.0f;
    if (tp < TT && xnd < avail) xv = x[((size_t)(nA+xnd)*TT + tp)*FF + xf];

    // ---- A fragments ----
    bf16x8 axh  = *(const bf16x8*)&Ax[t&1][0][lr][8*lg];
    bf16x8 axl  = *(const bf16x8*)&Ax[t&1][1][lr][8*lg];
    bf16x8 h0ah = *(const bf16x8*)&H0[rd0][0][lr][8*lg];
    bf16x8 h0al = *(const bf16x8*)&H0[rd0][1][lr][8*lg];
    bf16x8 h0bh = *(const bf16x8*)&H0[rd0][0][lr][32+8*lg];
    bf16x8 h0bl = *(const bf16x8*)&H0[rd0][1][lr][32+8*lg];

    __builtin_amdgcn_s_setprio(1);
    // ---- L0 gates(t): two tiles, single chain each, zero C-init ----
    f32x4 acc0, acc1;
    acc0 = __builtin_amdgcn_mfma_f32_16x16x32_bf16(axl, W0h[0][0], Z, 0, 0, 0);
    acc1 = __builtin_amdgcn_mfma_f32_16x16x32_bf16(axl, W0h[1][0], Z, 0, 0, 0);
    MFMA(acc0, axh,  W0l[0][0]); MFMA(acc0, axh,  W0h[0][0]);
    MFMA(acc1, axh,  W0l[1][0]); MFMA(acc1, axh,  W0h[1][0]);
    MFMA(acc0, h0al, W0h[0][1]); MFMA(acc0, h0ah, W0l[0][1]); MFMA(acc0, h0ah, W0h[0][1]);
    MFMA(acc1, h0al, W0h[1][1]); MFMA(acc1, h0ah, W0l[1][1]); MFMA(acc1, h0ah, W0h[1][1]);
    MFMA(acc0, h0bl, W0h[0][2]); MFMA(acc0, h0bh, W0l[0][2]); MFMA(acc0, h0bh, W0h[0][2]);
    MFMA(acc1, h0bl, W0h[1][2]); MFMA(acc1, h0bh, W0l[1][2]); MFMA(acc1, h0bh, W0h[1][2]);

    // ---- L1 gates(t-1) ----
    f32x4 acd0, acd1;
    if (t > 0){
      bf16x8 h1ah = *(const bf16x8*)&H1[rd1][0][lr][8*lg];
      bf16x8 h1al = *(const bf16x8*)&H1[rd1][1][lr][8*lg];
      bf16x8 h1bh = *(const bf16x8*)&H1[rd1][0][lr][32+8*lg];
      bf16x8 h1bl = *(const bf16x8*)&H1[rd1][1][lr][32+8*lg];
      acd0 = __builtin_amdgcn_mfma_f32_16x16x32_bf16(h0al, W1h[0][0], Z, 0, 0, 0);
      acd1 = __builtin_amdgcn_mfma_f32_16x16x32_bf16(h0al, W1h[1][0], Z, 0, 0, 0);
      MFMA(acd0, h0ah, W1l[0][0]); MFMA(acd0, h0ah, W1h[0][0]);
      MFMA(acd1, h0ah, W1l[1][0]); MFMA(acd1, h0ah, W1h[1][0]);
      MFMA(acd0, h0bl, W1h[0][1]); MFMA(acd0, h0bh, W1l[0][1]); MFMA(acd0, h0bh, W1h[0][1]);
      MFMA(acd1, h0bl, W1h[1][1]); MFMA(acd1, h0bh, W1l[1][1]); MFMA(acd1, h0bh, W1h[1][1]);
      MFMA(acd0, h1al, W1h[0][2]); MFMA(acd0, h1ah, W1l[0][2]); MFMA(acd0, h1ah, W1h[0][2]);
      MFMA(acd1, h1al, W1h[1][2]); MFMA(acd1, h1ah, W1l[1][2]); MFMA(acd1, h1ah, W1h[1][2]);
      MFMA(acd0, h1bl, W1h[0][3]); MFMA(acd0, h1bh, W1l[0][3]); MFMA(acd0, h1bh, W1h[0][3]);
      MFMA(acd1, h1bl, W1h[1][3]); MFMA(acd1, h1bh, W1l[1][3]); MFMA(acd1, h1bh, W1h[1][3]);
    }
    __builtin_amdgcn_s_setprio(0);

    // stage x(t+1) split (hidden under MFMA drain)
    if (tp < TT){
      unsigned short hh, hl; split2(xv, hh, hl);
      Ax[tp&1][0][xnd][xf] = (short)hh;
      Ax[tp&1][1][xnd][xf] = (short)hl;
    }

    // ---- in-register combine L0(t): bias folded into nonlinearities ----
    {
      f32x4 s0, s1;
      s0[0]=xor8(acc0[0]); s0[1]=xor8(acc0[1]); s0[2]=xor8(acc0[2]); s0[3]=xor8(acc0[3]);
      s1[0]=xor8(acc1[0]); s1[1]=xor8(acc1[1]); s1[2]=xor8(acc1[2]); s1[3]=xor8(acc1[3]);
      float gi_a = lo8 ? acc0[0] : s0[2],  gi_b = lo8 ? acc0[1] : s0[3];
      float gf_a = lo8 ? s0[0] : acc0[2],  gf_b = lo8 ? s0[1] : acc0[3];
      float gg_a = lo8 ? acc1[0] : s1[2],  gg_b = lo8 ? acc1[1] : s1[3];
      float go_a = lo8 ? s1[0] : acc1[2],  go_b = lo8 ? s1[1] : acc1[3];
      c0a = sigm_nb(gf_a, nb_f0)*c0a + sigm_nb(gi_a, nb_i0)*tanh_b(gg_a, b2_g0);
      float ha = sigm_nb(go_a, nb_o0)*tanh0(c0a);
      c0b = sigm_nb(gf_b, nb_f0)*c0b + sigm_nb(gi_b, nb_i0)*tanh_b(gg_b, b2_g0);
      float hb = sigm_nb(go_b, nb_o0)*tanh0(c0b);
      unsigned hi2, lo2; split_pk(ha, hb, hi2, lo2);
      H0[wr0][0][na][m] = (short)(hi2 & 0xFFFF);
      H0[wr0][0][nb][m] = (short)(hi2 >> 16);
      H0[wr0][1][na][m] = (short)(lo2 & 0xFFFF);
      H0[wr0][1][nb][m] = (short)(lo2 >> 16);
    }
    // ---- in-register combine L1(t-1) ----
    if (t > 0){
      f32x4 s0, s1;
      s0[0]=xor8(acd0[0]); s0[1]=xor8(acd0[1]); s0[2]=xor8(acd0[2]); s0[3]=xor8(acd0[3]);
      s1[0]=xor8(acd1[0]); s1[1]=xor8(acd1[1]); s1[2]=xor8(acd1[2]); s1[3]=xor8(acd1[3]);
      float gi_a = lo8 ? acd0[0] : s0[2],  gi_b = lo8 ? acd0[1] : s0[3];
      float gf_a = lo8 ? s0[0] : acd0[2],  gf_b = lo8 ? s0[1] : acd0[3];
      float gg_a = lo8 ? acd1[0] : s1[2],  gg_b = lo8 ? acd1[1] : s1[3];
      float go_a = lo8 ? s1[0] : acd1[2],  go_b = lo8 ? s1[1] : acd1[3];
      c1a = sigm_nb(gf_a, nb_f1)*c1a + sigm_nb(gi_a, nb_i1)*tanh_b(gg_a, b2_g1);
      float ha = sigm_nb(go_a, nb_o1)*tanh0(c1a);
      c1b = sigm_nb(gf_b, nb_f1)*c1b + sigm_nb(gi_b, nb_i1)*tanh_b(gg_b, b2_g1);
      float hb = sigm_nb(go_b, nb_o1)*tanh0(c1b);
      unsigned hi2, lo2; split_pk(ha, hb, hi2, lo2);
      H1[wr1][0][na][m] = (short)(hi2 & 0xFFFF);
      H1[wr1][0][nb][m] = (short)(hi2 >> 16);
      H1[wr1][1][na][m] = (short)(lo2 & 0xFFFF);
      H1[wr1][1][nb][m] = (short)(lo2 >> 16);
    }
    __syncthreads();   // single barrier per timestep
  }

  // ---- epilogue: L1 gates(TT-1) + combine -> hout ----
  {
    const int rd0 = (TT-1) & 1;      // h0(TT-1)
    const int rd1 =  TT & 1;         // h1(TT-2)
    bf16x8 h0ah = *(const bf16x8*)&H0[rd0][0][lr][8*lg];
    bf16x8 h0al = *(const bf16x8*)&H0[rd0][1][lr][8*lg];
    bf16x8 h0bh = *(const bf16x8*)&H0[rd0][0][lr][32+8*lg];
    bf16x8 h0bl = *(const bf16x8*)&H0[rd0][1][lr][32+8*lg];
    bf16x8 h1ah = *(const bf16x8*)&H1[rd1][0][lr][8*lg];
    bf16x8 h1al = *(const bf16x8*)&H1[rd1][1][lr][8*lg];
    bf16x8 h1bh = *(const bf16x8*)&H1[rd1][0][lr][32+8*lg];
    bf16x8 h1bl = *(const bf16x8*)&H1[rd1][1][lr][32+8*lg];
    f32x4 acd0 = __builtin_amdgcn_mfma_f32_16x16x32_bf16(h0al, W1h[0][0], Z, 0, 0, 0);
    f32x4 acd1 = __builtin_amdgcn_mfma_f32_16x16x32_bf16(h0al, W1h[1][0], Z, 0, 0, 0);
    MFMA(acd0, h0ah, W1l[0][0]); MFMA(acd0, h0ah, W1h[0][0]);
    MFMA(acd1, h0ah, W1l[1][0]); MFMA(acd1, h0ah, W1h[1][0]);
    MFMA(acd0, h0bl, W1h[0][1]); MFMA(acd0, h0bh, W1l[0][1]); MFMA(acd0, h0bh, W1h[0][1]);
    MFMA(acd1, h0bl, W1h[1][1]); MFMA(acd1, h0bh, W1l[1][1]); MFMA(acd1, h0bh, W1h[1][1]);
    MFMA(acd0, h1al, W1h[0][2]); MFMA(acd0, h1ah, W1l[0][2]); MFMA(acd0, h1ah, W1h[0][2]);
    MFMA(acd1, h1al, W1h[1][2]); MFMA(acd1, h1ah, W1l[1][2]); MFMA(acd1, h1ah, W1h[1][2]);
    MFMA(acd0, h1bl, W1h[0][3]); MFMA(acd0, h1bh, W1l[0][3]); MFMA(acd0, h1bh, W1h[0][3]);
    MFMA(acd1, h1bl, W1h[1][3]); MFMA(acd1, h1bh, W1l[1][3]); MFMA(acd1, h1bh, W1h[1][3]);

    f32x4 s0, s1;
    s0[0]=xor8(acd0[0]); s0[1]=xor8(acd0[1]); s0[2]=xor8(acd0[2]); s0[3]=xor8(acd0[3]);
    s1[0]=xor8(acd1[0]); s1[1]=xor8(acd1[1]); s1[2]=xor8(acd1[2]); s1[3]=xor8(acd1[3]);
    float gi_a = lo8 ? acd0[0] : s0[2],  gi_b = lo8 ? acd0[1] : s0[3];
    float gf_a = lo8 ? s0[0] : acd0[2],  gf_b = lo8 ? s0[1] : acd0[3];
    float gg_a = lo8 ? acd1[0] : s1[2],  gg_b = lo8 ? acd1[1] : s1[3];
    float go_a = lo8 ? s1[0] : acd1[2],  go_b = lo8 ? s1[1] : acd1[3];
    c1a = sigm_nb(gf_a, nb_f1)*c1a + sigm_nb(gi_a, nb_i1)*tanh_b(gg_a, b2_g1);
    float ha = sigm_nb(go_a, nb_o1)*tanh0(c1a);
    c1b = sigm_nb(gf_b, nb_f1)*c1b + sigm_nb(gi_b, nb_i1)*tanh_b(gg_b, b2_g1);
    float hb = sigm_nb(go_b, nb_o1)*tanh0(c1b);
    if (nA + na < n) hout[(size_t)(nA+na)*HH + m] = ha;
    if (nA + nb < n) hout[(size_t)(nA+nb)*HH + m] = hb;
  }
}

// ---------------------------------------------------------------------------
// GCN support kernels
// ---------------------------------------------------------------------------
__global__ void k_count(const int* __restrict__ dst, int E, int* __restrict__ cnt)
{
  int e = blockIdx.x * blockDim.x + threadIdx.x;
  if (e < E) atomicAdd(&cnt[dst[e]], 1);
}

__global__ void k_scan_build(const int* __restrict__ cnt, int n,
                             int* __restrict__ offs, int* __restrict__ cursor,
                             float* __restrict__ dinv)
{
  __shared__ int part[1024];
  const int tid = threadIdx.x;
  const int per = (n + 1023) >> 10;
  const int base = tid * per;
  int s = 0;
  for (int i = 0; i < per; ++i) { int idx = base + i; if (idx < n) s += cnt[idx]; }
  part[tid] = s;
  __syncthreads();
  for (int off = 1; off < 1024; off <<= 1) {
    int v = 0;
    if (tid >= off) v = part[tid - off];
    __syncthreads();
    part[tid] += v;
    __syncthreads();
  }
  int run = part[tid] - s;
  for (int i = 0; i < per; ++i) {
    int idx = base + i;
    if (idx < n) {
      offs[idx] = run; cursor[idx] = run;
      int c = cnt[idx];
      dinv[idx] = 1.0f / sqrtf((float)(c + 1));
      run += c;
    }
  }
}

__global__ void k_fill(const int* __restrict__ src, const int* __restrict__ dst,
                       int E, int* __restrict__ cursor, int* __restrict__ csr)
{
  int e = blockIdx.x * blockDim.x + threadIdx.x;
  if (e < E) {
    int d = dst[e];
    int pos = atomicAdd(&cursor[d], 1);
    csr[pos] = src[e];
  }
}

template <int K, int M>
__global__ void k_xw(const float* __restrict__ A, const float* __restrict__ W,
                     float* __restrict__ out, int n)
{
  int idx = blockIdx.x * blockDim.x + threadIdx.x;
  int row = idx / M, col = idx % M;
  if (row >= n) return;
  const float* a = A + (size_t)row * K;
  float acc = 0.0f;
#pragma unroll
  for (int k = 0; k < K; ++k) acc = fmaf(a[k], W[k*M + col], acc);
  out[(size_t)row*M + col] = acc;
}

// CSR aggregate for layer1 (FD=64) + bias/relu, FUSED with xw2 = g1 @ W2.
__global__ void k_agg_x2(const float* __restrict__ xw, const int* __restrict__ offs,
                         const int* __restrict__ cnt, const int* __restrict__ csr,
                         const float* __restrict__ dinv, const float* __restrict__ b,
                         const float* __restrict__ W2,
                         float* __restrict__ g1out, float* __restrict__ xw2out, int n)
{
  __shared__ float sg[4][GG1];
  const int nd   = threadIdx.x >> 6;
  const int lane = threadIdx.x & 63;
  const int node = blockIdx.x * 4 + nd;
  if (node < n) {
    const float di = dinv[node];
    float acc = xw[(size_t)node*GG1 + lane] * di * di;
    const int s0 = offs[node], e0 = s0 + cnt[node];
    for (int p = s0; p < e0; ++p) {
      int s = csr[p];
      acc = fmaf(xw[(size_t)s*GG1 + lane], dinv[s] * di, acc);
    }
    float val = fmaxf(acc + b[lane], 0.0f);
    g1out[(size_t)node*GG1 + lane] = val;
    sg[nd][lane] = val;
  }
  __syncthreads();
  if (node < n && lane < GG2) {
    float a2 = 0.0f;
#pragma unroll
    for (int k = 0; k < GG1; ++k) a2 = fmaf(sg[nd][k], W2[k*GG2 + lane], a2);
    xw2out[(size_t)node*GG2 + lane] = a2;
  }
}

template <int FD>
__global__ void k_agg(const float* __restrict__ xw, const int* __restrict__ offs,
                      const int* __restrict__ cnt, const int* __restrict__ csr,
                      const float* __restrict__ dinv, const float* __restrict__ b,
                      float* __restrict__ out, int n)
{
  int gidx = blockIdx.x * blockDim.x + threadIdx.x;
  int node = gidx / FD, lane = gidx % FD;
  if (node >= n) return;
  const float di = dinv[node];
  float acc = xw[(size_t)node*FD + lane] * di * di;
  const int s0 = offs[node], e0 = s0 + cnt[node];
  for (int p = s0; p < e0; ++p) {
    int s = csr[p];
    acc = fmaf(xw[(size_t)s*FD + lane], dinv[s] * di, acc);
  }
  out[(size_t)node*FD + lane] = fmaxf(acc + b[lane], 0.0f);
}

__global__ void k_fc(const float* __restrict__ g2, const int* __restrict__ sid,
                     const float* __restrict__ fcW, const float* __restrict__ fcb,
                     float* __restrict__ out, int n)
{
  int i = blockIdx.x * blockDim.x + threadIdx.x;
  if (i >= n) return;
  const float* row = g2 + (size_t)sid[i] * GG2;
  float acc = fcb[0];
#pragma unroll
  for (int f = 0; f < GG2; ++f) acc = fmaf(row[f], fcW[f], acc);
  out[i] = acc;
}

// ---------------------------------------------------------------------------
extern "C" void kernel_launch(void* const* d_in, const int* in_sizes, int n_in,
                              void* d_out, int out_size, void* d_ws, size_t ws_size,
                              hipStream_t stream)
{
  const float* x    = (const float*)d_in[0];
  const int*   sid  = (const int*)  d_in[1];
  const int*   eidx = (const int*)  d_in[2];
  const float* Wih0 = (const float*)d_in[3];
  const float* Whh0 = (const float*)d_in[4];
  const float* bih0 = (const float*)d_in[5];
  const float* bhh0 = (const float*)d_in[6];
  const float* Wih1 = (const float*)d_in[7];
  const float* Whh1 = (const float*)d_in[8];
  const float* bih1 = (const float*)d_in[9];
  const float* bhh1 = (const float*)d_in[10];
  const float* g1W  = (const float*)d_in[11];
  const float* g1b  = (const float*)d_in[12];
  const float* g2W  = (const float*)d_in[13];
  const float* g2b  = (const float*)d_in[14];
  const float* fcW  = (const float*)d_in[15];
  const float* fcb  = (const float*)d_in[16];

  const int n = in_sizes[1];
  const int E = in_sizes[2] / 2;
  float* out = (float*)d_out;

  char* w = (char*)d_ws;
  auto carve = [&](size_t bytes) -> void* {
    void* p = (void*)w; w += (bytes + 255) & ~(size_t)255; return p;
  };
  float* hfin   = (float*)carve((size_t)n * HH * 4);
  int*   cnt    = (int*)  carve((size_t)n * 4);
  int*   offs   = (int*)  carve((size_t)n * 4);
  int*   cursor = (int*)  carve((size_t)n * 4);
  float* dinv   = (float*)carve((size_t)n * 4);
  int*   csr    = (int*)  carve((size_t)E * 4);
  float* xw1    = (float*)carve((size_t)n * GG1 * 4);
  float* g1     = (float*)carve((size_t)n * GG1 * 4);
  float* xw2    = (float*)carve((size_t)n * GG2 * 4);
  float* g2     = (float*)carve((size_t)n * GG2 * 4);

  const int* src = eidx;
  const int* dst = eidx + E;

  lstm_mfma<<<(n + NN - 1) / NN, 512, 0, stream>>>(x, Wih0, Whh0, bih0, bhh0,
                                                   Wih1, Whh1, bih1, bhh1, hfin, n);

  hipMemsetAsync(cnt, 0, (size_t)n * 4, stream);
  k_count<<<(E + 255) / 256, 256, 0, stream>>>(dst, E, cnt);
  k_scan_build<<<1, 1024, 0, stream>>>(cnt, n, offs, cursor, dinv);
  k_fill<<<(E + 255) / 256, 256, 0, stream>>>(src, dst, E, cursor, csr);

  k_xw<HH, GG1><<<((size_t)n * GG1 + 255) / 256, 256, 0, stream>>>(hfin, g1W, xw1, n);
  k_agg_x2<<<(n + 3) / 4, 256, 0, stream>>>(xw1, offs, cnt, csr, dinv, g1b, g2W, g1, xw2, n);

  k_agg<GG2><<<((size_t)n * GG2 + 255) / 256, 256, 0, stream>>>(xw2, offs, cnt, csr, dinv, g2b, g2, n);

  k_fc<<<(n + 255) / 256, 256, 0, stream>>>(g2, sid, fcW, fcb, out, n);
}

// Round 12
// 683.394 us; speedup vs baseline: 1.3835x; 1.0191x over previous
//
#include <hip/hip_runtime.h>
#include <math.h>

#define TT 64
#define FF 32
#define HH 64
#define NN 16     // nodes per block
#define GG1 64
#define GG2 32

typedef float f32x4 __attribute__((ext_vector_type(4)));
typedef short bf16x8 __attribute__((ext_vector_type(8)));

__device__ __forceinline__ float fexp2(float x){ return __builtin_amdgcn_exp2f(x); }
__device__ __forceinline__ float frcp (float x){ return __builtin_amdgcn_rcpf(x); }
#define L2E 1.442695041f
__device__ __forceinline__ float sigm_nb(float v, float nb){
  return frcp(1.0f + fexp2(fmaf(v, -L2E, nb)));
}
__device__ __forceinline__ float tanh_b(float v, float b2){
  return fmaf(-2.0f, frcp(1.0f + fexp2(fmaf(v, 2.0f*L2E, b2))), 1.0f);
}
__device__ __forceinline__ float tanh0(float v){
  return fmaf(-2.0f, frcp(1.0f + fexp2(2.0f*L2E*v)), 1.0f);
}

// lane <-> lane^8 exchange within rows of 16 lanes (DPP row_ror:8, VALU pipe)
__device__ __forceinline__ float xor8(float v){
  int a = __builtin_bit_cast(int, v);
  int b = __builtin_amdgcn_update_dpp(0, a, 0x128, 0xF, 0xF, true);
  return __builtin_bit_cast(float, b);
}

__device__ __forceinline__ unsigned short bf16rn(float x){
  unsigned u = __builtin_bit_cast(unsigned, x);
  return (unsigned short)((u + 0x7FFFu + ((u >> 16) & 1u)) >> 16);
}
__device__ __forceinline__ void split2(float x, unsigned short& h, unsigned short& l){
  unsigned u = __builtin_bit_cast(unsigned, x);
  unsigned hr = (u + 0x7FFFu + ((u >> 16) & 1u)) & 0xFFFF0000u;
  h = (unsigned short)(hr >> 16);
  l = bf16rn(x - __builtin_bit_cast(float, hr));
}
// packed split of 2 values via v_cvt_pk_bf16_f32 (HW RNE)
__device__ __forceinline__ void split_pk(float a, float b, unsigned& hi2, unsigned& lo2){
  asm("v_cvt_pk_bf16_f32 %0, %1, %2" : "=v"(hi2) : "v"(a), "v"(b));
  float ha = __builtin_bit_cast(float, hi2 << 16);
  float hb = __builtin_bit_cast(float, hi2 & 0xFFFF0000u);
  float la = a - ha, lb = b - hb;
  asm("v_cvt_pk_bf16_f32 %0, %1, %2" : "=v"(lo2) : "v"(la), "v"(lb));
}

#define PIN(v) asm volatile("" : "+v"(v))
#define MFMA(acc, a, b) (acc) = __builtin_amdgcn_mfma_f32_16x16x32_bf16((a), (b), (acc), 0, 0, 0)

__device__ __forceinline__ void wsplit(const float* p, bf16x8& hi, bf16x8& lo){
  float4 a = *(const float4*)p;
  float4 b = *(const float4*)(p + 4);
  unsigned short h, s;
  split2(a.x,h,s); hi[0]=(short)h; lo[0]=(short)s;
  split2(a.y,h,s); hi[1]=(short)h; lo[1]=(short)s;
  split2(a.z,h,s); hi[2]=(short)h; lo[2]=(short)s;
  split2(a.w,h,s); hi[3]=(short)h; lo[3]=(short)s;
  split2(b.x,h,s); hi[4]=(short)h; lo[4]=(short)s;
  split2(b.y,h,s); hi[5]=(short)h; lo[5]=(short)s;
  split2(b.z,h,s); hi[6]=(short)h; lo[6]=(short)s;
  split2(b.w,h,s); hi[7]=(short)h; lo[7]=(short)s;
}

// ---------------------------------------------------------------------------
// Fused 2-layer LSTM on MFMA, bf16 hi/lo emulated-fp32 (3-pass), in-register
// DPP combine. ROUND-12: role-split 16-wave block at 4 waves/SIMD.
// Waves 0-7 own layer-0 tile-pairs (i|f + g|o) of col-group w: 18 MFMA +
// combine L0(t) + x staging. Waves 8-15 own layer-1 tile-pairs: 24 MFMA +
// combine L1(t-1). Per-wave regs ~115-125 <= 128 so the whole block fits one
// CU at 4 waves/SIMD; each SIMD hosts 2 L0 + 2 L1 waves whose MFMA and
// trans-heavy combine phases interleave. Pipeline + numerics unchanged.
// ---------------------------------------------------------------------------
__global__ __launch_bounds__(1024, 4)
void lstm_mfma(const float* __restrict__ x,
    const float* __restrict__ Wih0, const float* __restrict__ Whh0,
    const float* __restrict__ bih0, const float* __restrict__ bhh0,
    const float* __restrict__ Wih1, const float* __restrict__ Whh1,
    const float* __restrict__ bih1, const float* __restrict__ bhh1,
    float* __restrict__ hout, int n)
{
  const int tid  = threadIdx.x;
  const int wv   = tid >> 6;     // wave 0..15
  const int role = wv >> 3;      // 0 = layer0 waves, 1 = layer1 waves
  const int w    = wv & 7;       // col-group within role
  const int l    = tid & 63;
  const int lr   = l & 15;       // A row (node) / B,D col-slot
  const int lg   = l >> 4;       // k-group 0..3
  const int nA   = blockIdx.x * NN;
  int avail = n - nA; if (avail > NN) avail = NN;

  __shared__ short Ax[2][2][16][40];   // [buf][hi/lo][node][f]   80B rows
  __shared__ short H0[2][2][16][88];   // [buf][hi/lo][node][m]  176B rows
  __shared__ short H1[2][2][16][88];

  const int jm   = lr & 7;
  const bool lo8 = (lr < 8);
  const int col0 = lo8 ? (8*w + jm) : (64  + 8*w + jm);       // i | f
  const int col1 = lo8 ? (128 + 8*w + jm) : (192 + 8*w + jm); // g | o

  // ---- role-dependent weights -> split register fragments ----
  // role 0: [0]=x k0-31, [1]=h0 k0-31, [2]=h0 k32-63   (12 frags)
  // role 1: [0]=h0 k0-31, [1]=h0 k32-63, [2]=h1 k0-31, [3]=h1 k32-63 (16)
  bf16x8 Wh[2][4], Wl[2][4];
  if (role == 0){
#pragma unroll
    for (int h = 0; h < 2; ++h){
      const int col = h ? col1 : col0;
      wsplit(Wih0 + col*FF + 8*lg,      Wh[h][0], Wl[h][0]);
      wsplit(Whh0 + col*HH + 8*lg,      Wh[h][1], Wl[h][1]);
      wsplit(Whh0 + col*HH + 32 + 8*lg, Wh[h][2], Wl[h][2]);
      Wh[h][3] = Wh[h][2]; Wl[h][3] = Wl[h][2];   // unused, keep defined
    }
  } else {
#pragma unroll
    for (int h = 0; h < 2; ++h){
      const int col = h ? col1 : col0;
      wsplit(Wih1 + col*HH + 8*lg,      Wh[h][0], Wl[h][0]);
      wsplit(Wih1 + col*HH + 32 + 8*lg, Wh[h][1], Wl[h][1]);
      wsplit(Whh1 + col*HH + 8*lg,      Wh[h][2], Wl[h][2]);
      wsplit(Whh1 + col*HH + 32 + 8*lg, Wh[h][3], Wl[h][3]);
    }
  }
#pragma unroll
  for (int h = 0; h < 2; ++h)
#pragma unroll
    for (int k = 0; k < 4; ++k){ PIN(Wh[h][k]); PIN(Wl[h][k]); }

  // ---- per-lane pre-scaled gate biases for this role's layer, col m ----
  const int m = 8*w + jm;
  const float* bi = role ? bih1 : bih0;
  const float* bh = role ? bhh1 : bhh0;
  const float nb_i = -L2E      * (bi[m      ] + bh[m      ]);
  const float nb_f = -L2E      * (bi[m +  64] + bh[m +  64]);
  const float b2_g =  2.0f*L2E * (bi[m + 128] + bh[m + 128]);
  const float nb_o = -L2E      * (bi[m + 192] + bh[m + 192]);

  // ---- zero h planes; stage x(0) ----
  {
    short* p0 = &H0[0][0][0][0];
    short* p1 = &H1[0][0][0][0];
    for (int i = tid; i < 2*2*16*88; i += 1024){ p0[i] = 0; p1[i] = 0; }
    if (tid < 512){
      const int xnd = tid >> 5, xf = tid & 31;
      float v = (xnd < avail) ? x[((size_t)(nA+xnd)*TT + 0)*FF + xf] : 0.0f;
      unsigned short hh, hl; split2(v, hh, hl);
      Ax[0][0][xnd][xf] = (short)hh;
      Ax[0][1][xnd][xf] = (short)hl;
    }
  }
  const int na = 4*lg + (lo8 ? 0 : 2);
  const int nb = na + 1;
  float ca = 0.0f, cb = 0.0f;    // this role's 2 cells at (na,m),(nb,m)
  const f32x4 Z = {0.f, 0.f, 0.f, 0.f};
  __syncthreads();

  for (int t = 0; t < TT; ++t){
    const int rd0 = (t & 1) ^ 1;   // h0(t-1)
    const int wr0 =  t & 1;        // h0(t)
    const int rd1 =  t & 1;        // h1(t-2)
    const int wr1 = (t & 1) ^ 1;   // h1(t-1)

    if (role == 0){
      // ---- L0 waves: gates L0(t), x staging, combine -> h0(t) ----
      const int xnd = tid >> 5, xf = tid & 31;
      const int tp = t + 1;
      float xv = 0.0f;
      if (tp < TT && xnd < avail) xv = x[((size_t)(nA+xnd)*TT + tp)*FF + xf];

      bf16x8 axh  = *(const bf16x8*)&Ax[t&1][0][lr][8*lg];
      bf16x8 axl  = *(const bf16x8*)&Ax[t&1][1][lr][8*lg];
      bf16x8 h0ah = *(const bf16x8*)&H0[rd0][0][lr][8*lg];
      bf16x8 h0al = *(const bf16x8*)&H0[rd0][1][lr][8*lg];
      bf16x8 h0bh = *(const bf16x8*)&H0[rd0][0][lr][32+8*lg];
      bf16x8 h0bl = *(const bf16x8*)&H0[rd0][1][lr][32+8*lg];

      __builtin_amdgcn_s_setprio(1);
      f32x4 A0, A1;
      A0 = __builtin_amdgcn_mfma_f32_16x16x32_bf16(axl, Wh[0][0], Z, 0, 0, 0);
      A1 = __builtin_amdgcn_mfma_f32_16x16x32_bf16(axl, Wh[1][0], Z, 0, 0, 0);
      MFMA(A0, axh,  Wl[0][0]); MFMA(A0, axh,  Wh[0][0]);
      MFMA(A1, axh,  Wl[1][0]); MFMA(A1, axh,  Wh[1][0]);
      MFMA(A0, h0al, Wh[0][1]); MFMA(A0, h0ah, Wl[0][1]); MFMA(A0, h0ah, Wh[0][1]);
      MFMA(A1, h0al, Wh[1][1]); MFMA(A1, h0ah, Wl[1][1]); MFMA(A1, h0ah, Wh[1][1]);
      MFMA(A0, h0bl, Wh[0][2]); MFMA(A0, h0bh, Wl[0][2]); MFMA(A0, h0bh, Wh[0][2]);
      MFMA(A1, h0bl, Wh[1][2]); MFMA(A1, h0bh, Wl[1][2]); MFMA(A1, h0bh, Wh[1][2]);
      __builtin_amdgcn_s_setprio(0);

      if (tp < TT){
        unsigned short hh, hl; split2(xv, hh, hl);
        Ax[tp&1][0][xnd][xf] = (short)hh;
        Ax[tp&1][1][xnd][xf] = (short)hl;
      }

      f32x4 s0, s1;
      s0[0]=xor8(A0[0]); s0[1]=xor8(A0[1]); s0[2]=xor8(A0[2]); s0[3]=xor8(A0[3]);
      s1[0]=xor8(A1[0]); s1[1]=xor8(A1[1]); s1[2]=xor8(A1[2]); s1[3]=xor8(A1[3]);
      float gi_a = lo8 ? A0[0] : s0[2],  gi_b = lo8 ? A0[1] : s0[3];
      float gf_a = lo8 ? s0[0] : A0[2],  gf_b = lo8 ? s0[1] : A0[3];
      float gg_a = lo8 ? A1[0] : s1[2],  gg_b = lo8 ? A1[1] : s1[3];
      float go_a = lo8 ? s1[0] : A1[2],  go_b = lo8 ? s1[1] : A1[3];
      ca = sigm_nb(gf_a, nb_f)*ca + sigm_nb(gi_a, nb_i)*tanh_b(gg_a, b2_g);
      float ha = sigm_nb(go_a, nb_o)*tanh0(ca);
      cb = sigm_nb(gf_b, nb_f)*cb + sigm_nb(gi_b, nb_i)*tanh_b(gg_b, b2_g);
      float hb = sigm_nb(go_b, nb_o)*tanh0(cb);
      unsigned hi2, lo2; split_pk(ha, hb, hi2, lo2);
      H0[wr0][0][na][m] = (short)(hi2 & 0xFFFF);
      H0[wr0][0][nb][m] = (short)(hi2 >> 16);
      H0[wr0][1][na][m] = (short)(lo2 & 0xFFFF);
      H0[wr0][1][nb][m] = (short)(lo2 >> 16);
    }
    else if (t > 0){
      // ---- L1 waves: gates L1(t-1), combine -> h1(t-1) ----
      bf16x8 h0ah = *(const bf16x8*)&H0[rd0][0][lr][8*lg];
      bf16x8 h0al = *(const bf16x8*)&H0[rd0][1][lr][8*lg];
      bf16x8 h0bh = *(const bf16x8*)&H0[rd0][0][lr][32+8*lg];
      bf16x8 h0bl = *(const bf16x8*)&H0[rd0][1][lr][32+8*lg];

      __builtin_amdgcn_s_setprio(1);
      f32x4 D0, D1;
      D0 = __builtin_amdgcn_mfma_f32_16x16x32_bf16(h0al, Wh[0][0], Z, 0, 0, 0);
      D1 = __builtin_amdgcn_mfma_f32_16x16x32_bf16(h0al, Wh[1][0], Z, 0, 0, 0);
      MFMA(D0, h0ah, Wl[0][0]); MFMA(D0, h0ah, Wh[0][0]);
      MFMA(D1, h0ah, Wl[1][0]); MFMA(D1, h0ah, Wh[1][0]);
      MFMA(D0, h0bl, Wh[0][1]); MFMA(D0, h0bh, Wl[0][1]); MFMA(D0, h0bh, Wh[0][1]);
      MFMA(D1, h0bl, Wh[1][1]); MFMA(D1, h0bh, Wl[1][1]); MFMA(D1, h0bh, Wh[1][1]);
      // h1 fragments loaded after the h0 half to limit register liveness
      bf16x8 h1ah = *(const bf16x8*)&H1[rd1][0][lr][8*lg];
      bf16x8 h1al = *(const bf16x8*)&H1[rd1][1][lr][8*lg];
      bf16x8 h1bh = *(const bf16x8*)&H1[rd1][0][lr][32+8*lg];
      bf16x8 h1bl = *(const bf16x8*)&H1[rd1][1][lr][32+8*lg];
      MFMA(D0, h1al, Wh[0][2]); MFMA(D0, h1ah, Wl[0][2]); MFMA(D0, h1ah, Wh[0][2]);
      MFMA(D1, h1al, Wh[1][2]); MFMA(D1, h1ah, Wl[1][2]); MFMA(D1, h1ah, Wh[1][2]);
      MFMA(D0, h1bl, Wh[0][3]); MFMA(D0, h1bh, Wl[0][3]); MFMA(D0, h1bh, Wh[0][3]);
      MFMA(D1, h1bl, Wh[1][3]); MFMA(D1, h1bh, Wl[1][3]); MFMA(D1, h1bh, Wh[1][3]);
      __builtin_amdgcn_s_setprio(0);

      f32x4 s0, s1;
      s0[0]=xor8(D0[0]); s0[1]=xor8(D0[1]); s0[2]=xor8(D0[2]); s0[3]=xor8(D0[3]);
      s1[0]=xor8(D1[0]); s1[1]=xor8(D1[1]); s1[2]=xor8(D1[2]); s1[3]=xor8(D1[3]);
      float gi_a = lo8 ? D0[0] : s0[2],  gi_b = lo8 ? D0[1] : s0[3];
      float gf_a = lo8 ? s0[0] : D0[2],  gf_b = lo8 ? s0[1] : D0[3];
      float gg_a = lo8 ? D1[0] : s1[2],  gg_b = lo8 ? D1[1] : s1[3];
      float go_a = lo8 ? s1[0] : D1[2],  go_b = lo8 ? s1[1] : D1[3];
      ca = sigm_nb(gf_a, nb_f)*ca + sigm_nb(gi_a, nb_i)*tanh_b(gg_a, b2_g);
      float ha = sigm_nb(go_a, nb_o)*tanh0(ca);
      cb = sigm_nb(gf_b, nb_f)*cb + sigm_nb(gi_b, nb_i)*tanh_b(gg_b, b2_g);
      float hb = sigm_nb(go_b, nb_o)*tanh0(cb);
      unsigned hi2, lo2; split_pk(ha, hb, hi2, lo2);
      H1[wr1][0][na][m] = (short)(hi2 & 0xFFFF);
      H1[wr1][0][nb][m] = (short)(hi2 >> 16);
      H1[wr1][1][na][m] = (short)(lo2 & 0xFFFF);
      H1[wr1][1][nb][m] = (short)(lo2 >> 16);
    }
    __syncthreads();   // single barrier per timestep
  }

  // ---- epilogue (L1 waves): gates L1(TT-1) + combine -> hout ----
  if (role == 1){
    const int rd0 = (TT-1) & 1;      // h0(TT-1)
    const int rd1 =  TT & 1;         // h1(TT-2)
    bf16x8 h0ah = *(const bf16x8*)&H0[rd0][0][lr][8*lg];
    bf16x8 h0al = *(const bf16x8*)&H0[rd0][1][lr][8*lg];
    bf16x8 h0bh = *(const bf16x8*)&H0[rd0][0][lr][32+8*lg];
    bf16x8 h0bl = *(const bf16x8*)&H0[rd0][1][lr][32+8*lg];
    bf16x8 h1ah = *(const bf16x8*)&H1[rd1][0][lr][8*lg];
    bf16x8 h1al = *(const bf16x8*)&H1[rd1][1][lr][8*lg];
    bf16x8 h1bh = *(const bf16x8*)&H1[rd1][0][lr][32+8*lg];
    bf16x8 h1bl = *(const bf16x8*)&H1[rd1][1][lr][32+8*lg];
    f32x4 D0 = __builtin_amdgcn_mfma_f32_16x16x32_bf16(h0al, Wh[0][0], Z, 0, 0, 0);
    f32x4 D1 = __builtin_amdgcn_mfma_f32_16x16x32_bf16(h0al, Wh[1][0], Z, 0, 0, 0);
    MFMA(D0, h0ah, Wl[0][0]); MFMA(D0, h0ah, Wh[0][0]);
    MFMA(D1, h0ah, Wl[1][0]); MFMA(D1, h0ah, Wh[1][0]);
    MFMA(D0, h0bl, Wh[0][1]); MFMA(D0, h0bh, Wl[0][1]); MFMA(D0, h0bh, Wh[0][1]);
    MFMA(D1, h0bl, Wh[1][1]); MFMA(D1, h0bh, Wl[1][1]); MFMA(D1, h0bh, Wh[1][1]);
    MFMA(D0, h1al, Wh[0][2]); MFMA(D0, h1ah, Wl[0][2]); MFMA(D0, h1ah, Wh[0][2]);
    MFMA(D1, h1al, Wh[1][2]); MFMA(D1, h1ah, Wl[1][2]); MFMA(D1, h1ah, Wh[1][2]);
    MFMA(D0, h1bl, Wh[0][3]); MFMA(D0, h1bh, Wl[0][3]); MFMA(D0, h1bh, Wh[0][3]);
    MFMA(D1, h1bl, Wh[1][3]); MFMA(D1, h1bh, Wl[1][3]); MFMA(D1, h1bh, Wh[1][3]);

    f32x4 s0, s1;
    s0[0]=xor8(D0[0]); s0[1]=xor8(D0[1]); s0[2]=xor8(D0[2]); s0[3]=xor8(D0[3]);
    s1[0]=xor8(D1[0]); s1[1]=xor8(D1[1]); s1[2]=xor8(D1[2]); s1[3]=xor8(D1[3]);
    float gi_a = lo8 ? D0[0] : s0[2],  gi_b = lo8 ? D0[1] : s0[3];
    float gf_a = lo8 ? s0[0] : D0[2],  gf_b = lo8 ? s0[1] : D0[3];
    float gg_a = lo8 ? D1[0] : s1[2],  gg_b = lo8 ? D1[1] : s1[3];
    float go_a = lo8 ? s1[0] : D1[2],  go_b = lo8 ? s1[1] : D1[3];
    ca = sigm_nb(gf_a, nb_f)*ca + sigm_nb(gi_a, nb_i)*tanh_b(gg_a, b2_g);
    float ha = sigm_nb(go_a, nb_o)*tanh0(ca);
    cb = sigm_nb(gf_b, nb_f)*cb + sigm_nb(gi_b, nb_i)*tanh_b(gg_b, b2_g);
    float hb = sigm_nb(go_b, nb_o)*tanh0(cb);
    if (nA + na < n) hout[(size_t)(nA+na)*HH + m] = ha;
    if (nA + nb < n) hout[(size_t)(nA+nb)*HH + m] = hb;
  }
}

// ---------------------------------------------------------------------------
// GCN support kernels
// ---------------------------------------------------------------------------
__global__ void k_count(const int* __restrict__ dst, int E, int* __restrict__ cnt)
{
  int e = blockIdx.x * blockDim.x + threadIdx.x;
  if (e < E) atomicAdd(&cnt[dst[e]], 1);
}

__global__ void k_scan_build(const int* __restrict__ cnt, int n,
                             int* __restrict__ offs, int* __restrict__ cursor,
                             float* __restrict__ dinv)
{
  __shared__ int part[1024];
  const int tid = threadIdx.x;
  const int per = (n + 1023) >> 10;
  const int base = tid * per;
  int s = 0;
  for (int i = 0; i < per; ++i) { int idx = base + i; if (idx < n) s += cnt[idx]; }
  part[tid] = s;
  __syncthreads();
  for (int off = 1; off < 1024; off <<= 1) {
    int v = 0;
    if (tid >= off) v = part[tid - off];
    __syncthreads();
    part[tid] += v;
    __syncthreads();
  }
  int run = part[tid] - s;
  for (int i = 0; i < per; ++i) {
    int idx = base + i;
    if (idx < n) {
      offs[idx] = run; cursor[idx] = run;
      int c = cnt[idx];
      dinv[idx] = 1.0f / sqrtf((float)(c + 1));
      run += c;
    }
  }
}

__global__ void k_fill(const int* __restrict__ src, const int* __restrict__ dst,
                       int E, int* __restrict__ cursor, int* __restrict__ csr)
{
  int e = blockIdx.x * blockDim.x + threadIdx.x;
  if (e < E) {
    int d = dst[e];
    int pos = atomicAdd(&cursor[d], 1);
    csr[pos] = src[e];
  }
}

template <int K, int M>
__global__ void k_xw(const float* __restrict__ A, const float* __restrict__ W,
                     float* __restrict__ out, int n)
{
  int idx = blockIdx.x * blockDim.x + threadIdx.x;
  int row = idx / M, col = idx % M;
  if (row >= n) return;
  const float* a = A + (size_t)row * K;
  float acc = 0.0f;
#pragma unroll
  for (int k = 0; k < K; ++k) acc = fmaf(a[k], W[k*M + col], acc);
  out[(size_t)row*M + col] = acc;
}

// CSR aggregate for layer1 (FD=64) + bias/relu, FUSED with xw2 = g1 @ W2.
__global__ void k_agg_x2(const float* __restrict__ xw, const int* __restrict__ offs,
                         const int* __restrict__ cnt, const int* __restrict__ csr,
                         const float* __restrict__ dinv, const float* __restrict__ b,
                         const float* __restrict__ W2,
                         float* __restrict__ g1out, float* __restrict__ xw2out, int n)
{
  __shared__ float sg[4][GG1];
  const int nd   = threadIdx.x >> 6;
  const int lane = threadIdx.x & 63;
  const int node = blockIdx.x * 4 + nd;
  if (node < n) {
    const float di = dinv[node];
    float acc = xw[(size_t)node*GG1 + lane] * di * di;
    const int s0 = offs[node], e0 = s0 + cnt[node];
    for (int p = s0; p < e0; ++p) {
      int s = csr[p];
      acc = fmaf(xw[(size_t)s*GG1 + lane], dinv[s] * di, acc);
    }
    float val = fmaxf(acc + b[lane], 0.0f);
    g1out[(size_t)node*GG1 + lane] = val;
    sg[nd][lane] = val;
  }
  __syncthreads();
  if (node < n && lane < GG2) {
    float a2 = 0.0f;
#pragma unroll
    for (int k = 0; k < GG1; ++k) a2 = fmaf(sg[nd][k], W2[k*GG2 + lane], a2);
    xw2out[(size_t)node*GG2 + lane] = a2;
  }
}

template <int FD>
__global__ void k_agg(const float* __restrict__ xw, const int* __restrict__ offs,
                      const int* __restrict__ cnt, const int* __restrict__ csr,
                      const float* __restrict__ dinv, const float* __restrict__ b,
                      float* __restrict__ out, int n)
{
  int gidx = blockIdx.x * blockDim.x + threadIdx.x;
  int node = gidx / FD, lane = gidx % FD;
  if (node >= n) return;
  const float di = dinv[node];
  float acc = xw[(size_t)node*FD + lane] * di * di;
  const int s0 = offs[node], e0 = s0 + cnt[node];
  for (int p = s0; p < e0; ++p) {
    int s = csr[p];
    acc = fmaf(xw[(size_t)s*FD + lane], dinv[s] * di, acc);
  }
  out[(size_t)node*FD + lane] = fmaxf(acc + b[lane], 0.0f);
}

__global__ void k_fc(const float* __restrict__ g2, const int* __restrict__ sid,
                     const float* __restrict__ fcW, const float* __restrict__ fcb,
                     float* __restrict__ out, int n)
{
  int i = blockIdx.x * blockDim.x + threadIdx.x;
  if (i >= n) return;
  const float* row = g2 + (size_t)sid[i] * GG2;
  float acc = fcb[0];
#pragma unroll
  for (int f = 0; f < GG2; ++f) acc = fmaf(row[f], fcW[f], acc);
  out[i] = acc;
}

// ---------------------------------------------------------------------------
extern "C" void kernel_launch(void* const* d_in, const int* in_sizes, int n_in,
                              void* d_out, int out_size, void* d_ws, size_t ws_size,
                              hipStream_t stream)
{
  const float* x    = (const float*)d_in[0];
  const int*   sid  = (const int*)  d_in[1];
  const int*   eidx = (const int*)  d_in[2];
  const float* Wih0 = (const float*)d_in[3];
  const float* Whh0 = (const float*)d_in[4];
  const float* bih0 = (const float*)d_in[5];
  const float* bhh0 = (const float*)d_in[6];
  const float* Wih1 = (const float*)d_in[7];
  const float* Whh1 = (const float*)d_in[8];
  const float* bih1 = (const float*)d_in[9];
  const float* bhh1 = (const float*)d_in[10];
  const float* g1W  = (const float*)d_in[11];
  const float* g1b  = (const float*)d_in[12];
  const float* g2W  = (const float*)d_in[13];
  const float* g2b  = (const float*)d_in[14];
  const float* fcW  = (const float*)d_in[15];
  const float* fcb  = (const float*)d_in[16];

  const int n = in_sizes[1];
  const int E = in_sizes[2] / 2;
  float* out = (float*)d_out;

  char* w = (char*)d_ws;
  auto carve = [&](size_t bytes) -> void* {
    void* p = (void*)w; w += (bytes + 255) & ~(size_t)255; return p;
  };
  float* hfin   = (float*)carve((size_t)n * HH * 4);
  int*   cnt    = (int*)  carve((size_t)n * 4);
  int*   offs   = (int*)  carve((size_t)n * 4);
  int*   cursor = (int*)  carve((size_t)n * 4);
  float* dinv   = (float*)carve((size_t)n * 4);
  int*   csr    = (int*)  carve((size_t)E * 4);
  float* xw1    = (float*)carve((size_t)n * GG1 * 4);
  float* g1     = (float*)carve((size_t)n * GG1 * 4);
  float* xw2    = (float*)carve((size_t)n * GG2 * 4);
  float* g2     = (float*)carve((size_t)n * GG2 * 4);

  const int* src = eidx;
  const int* dst = eidx + E;

  lstm_mfma<<<(n + NN - 1) / NN, 1024, 0, stream>>>(x, Wih0, Whh0, bih0, bhh0,
                                                    Wih1, Whh1, bih1, bhh1, hfin, n);

  hipMemsetAsync(cnt, 0, (size_t)n * 4, stream);
  k_count<<<(E + 255) / 256, 256, 0, stream>>>(dst, E, cnt);
  k_scan_build<<<1, 1024, 0, stream>>>(cnt, n, offs, cursor, dinv);
  k_fill<<<(E + 255) / 256, 256, 0, stream>>>(src, dst, E, cursor, csr);

  k_xw<HH, GG1><<<((size_t)n * GG1 + 255) / 256, 256, 0, stream>>>(hfin, g1W, xw1, n);
  k_agg_x2<<<(n + 3) / 4, 256, 0, stream>>>(xw1, offs, cnt, csr, dinv, g1b, g2W, g1, xw2, n);

  k_agg<GG2><<<((size_t)n * GG2 + 255) / 256, 256, 0, stream>>>(xw2, offs, cnt, csr, dinv, g2b, g2, n);

  k_fc<<<(n + 255) / 256, 256, 0, stream>>>(g2, sid, fcW, fcb, out, n);
}